// Round 17
// baseline (540.008 us; speedup 1.0000x reference)
//
#include <hip/hip_runtime.h>
#include <cstdint>
#include <cstddef>

#define NU 500000
#define NI 50000
#define NE 1000000
#define HC 128   // H*C
#define NH 4

typedef __attribute__((ext_vector_type(8))) short bf16x8;
typedef __attribute__((ext_vector_type(4))) float f32x4;

union frag_u { bf16x8 v; unsigned int u[4]; };

// bf16 pack/unpack (RNE)
__device__ __forceinline__ unsigned int pack_bf2(float x, float y) {
    unsigned int r;
    asm("v_cvt_pk_bf16_f32 %0, %1, %2" : "=v"(r) : "v"(x), "v"(y));
    return r;
}
__device__ __forceinline__ float2 unpack_bf2(unsigned int v) {
    return make_float2(__uint_as_float(v << 16),
                       __uint_as_float(v & 0xffff0000u));
}
__device__ __forceinline__ unsigned short pack_bf1(float x) {
    unsigned int b = __float_as_uint(x);
    b += 0x7fffu + ((b >> 16) & 1u);
    return (unsigned short)(b >> 16);
}

__device__ __forceinline__ float head_reduce(float p) {
    p += __shfl_xor(p, 8, 16);
    p += __shfl_xor(p, 4, 16);
    p += __shfl_xor(p, 2, 16);
    p += __shfl_xor(p, 1, 16);
    return p;
}

// ---------------------------------------------------------------------------
// Weight prep: Bp holds 3 matrices in MFMA fragment order, bf16.
// ---------------------------------------------------------------------------
__global__ void wprep(const float* __restrict__ user_W, const float* __restrict__ user_b,
                      const float* __restrict__ c1_Wl, const float* __restrict__ c1_bl,
                      const float* __restrict__ c2_Wr, const float* __restrict__ c2_br,
                      const float* __restrict__ c2_Wl, unsigned short* __restrict__ Bp)
{
    const int t = blockIdx.x * 256 + threadIdx.x;   // 0..49151
    const int mat = t >> 14;
    const int k = (t >> 7) & 127;
    const int n = t & 127;
    float val = 0.f;
    if (mat == 2) {
        val = c2_Wl[k * 128 + n];
    } else {
        const float* W2 = mat ? c2_Wr : c1_Wl;
        if (k < 101) {
            for (int q = 0; q < 32; ++q) val = fmaf(user_W[k * 32 + q], W2[q * 128 + n], val);
        } else if (k == 101) {
            for (int q = 0; q < 32; ++q) val = fmaf(user_b[q], W2[q * 128 + n], val);
            val += (mat ? c2_br : c1_bl)[n];
        }
    }
    const int fi = (mat * 8 + (n >> 4)) * 4 + (k >> 5);
    const int lane_ = (n & 15) + ((k >> 3) & 3) * 16;
    Bp[(size_t)fi * 512 + lane_ * 8 + (k & 7)] = pack_bf1(val);
}

// ---------------------------------------------------------------------------
// W1 (classifier, 128x64) -> fragment order, 16 frags
// ---------------------------------------------------------------------------
__global__ void w1prep(const float* __restrict__ W1, unsigned short* __restrict__ Bp1)
{
    const int t = blockIdx.x * 256 + threadIdx.x;   // 0..8191
    const int k = t >> 6;
    const int n = t & 63;
    const float val = W1[k * 64 + n];
    const int fi = (n >> 4) * 4 + (k >> 5);
    const int lane_ = (n & 15) + ((k >> 3) & 3) * 16;
    Bp1[(size_t)fi * 512 + lane_ * 8 + (k & 7)] = pack_bf1(val);
}

// ---------------------------------------------------------------------------
// xr1 rank-1 weights: wv[j] = item_W@c1_Wr, bb[j] = item_b@c1_Wr + c1_br
// ---------------------------------------------------------------------------
__global__ void wvbb_prep(const float* __restrict__ item_W, const float* __restrict__ item_b,
                          const float* __restrict__ c1_Wr, const float* __restrict__ c1_br,
                          float* __restrict__ wvbb)
{
    const int j = threadIdx.x;
    if (j >= 128) return;
    float wv = 0.f, bb = 0.f;
    for (int q = 0; q < 32; ++q) {
        wv = fmaf(item_W[q], c1_Wr[q * 128 + j], wv);
        bb = fmaf(item_b[q], c1_Wr[q * 128 + j], bb);
    }
    wvbb[j] = wv;
    wvbb[128 + j] = bb + c1_br[j];
}

// ---------------------------------------------------------------------------
// MFMA: [NU,101(+bias)] fp32 @ Wc{1,2} -> xl1, xr2 (bf16).
// Block = 128 threads / 32 rows (LDS 13.8KB -> ~11 blocks/CU, higher occ).
// Wave = 16 rows x 256 cols; xpo transpose slab pitch 140 hw (conflict-free).
// ---------------------------------------------------------------------------
__global__ __launch_bounds__(128)
void mfma_user(const float* __restrict__ cx, const unsigned short* __restrict__ Bp,
               unsigned short* __restrict__ outL, unsigned short* __restrict__ outR, int M)
{
    __shared__ float xs[32 * 108];   // 13824 B

    const int tid = threadIdx.x;     // 0..127
    const int lane = tid & 63;
    const int wid = tid >> 6;        // 0..1
    const int rowblk = blockIdx.x * 32;   // NU % 32 == 0 -> full blocks

    // stage: source region is contiguous (row pitch = 101 floats)
    const float* src = cx + (size_t)rowblk * 101;
    const int total = 32 * 101;
    for (int i = tid; i < total; i += 128) {
        const int r = i / 101;
        const int c = i - r * 101;
        xs[r * 108 + c] = src[i];
    }
    __syncthreads();

    const int rowbase = wid * 16;
    const int row = lane & 15;
    const int chunk = lane >> 4;
    const float* rowp = xs + (rowbase + row) * 108;

    frag_u a[4];
    #pragma unroll
    for (int ks = 0; ks < 3; ++ks) {
        const int kb = ks * 32 + chunk * 8;
        const float4 p = *(const float4*)(rowp + kb);
        const float4 q = *(const float4*)(rowp + kb + 4);
        a[ks].u[0] = pack_bf2(p.x, p.y);
        a[ks].u[1] = pack_bf2(p.z, p.w);
        a[ks].u[2] = pack_bf2(q.x, q.y);
        a[ks].u[3] = pack_bf2(q.z, q.w);
    }
    {   // kstep 3: k 96..100 real, k=101 -> 1.0 (bias row), rest 0
        float v0 = 0.f, v1 = 0.f, v2 = 0.f, v3 = 0.f, v4 = 0.f, v5 = 0.f;
        if (chunk == 0) {
            const float4 p = *(const float4*)(rowp + 96);
            v0 = p.x; v1 = p.y; v2 = p.z; v3 = p.w;
            v4 = rowp[100];
            v5 = 1.0f;
        }
        a[3].u[0] = pack_bf2(v0, v1);
        a[3].u[1] = pack_bf2(v2, v3);
        a[3].u[2] = pack_bf2(v4, v5);
        a[3].u[3] = 0u;
    }

    // per-wave output slab overlays this wave's own staging region
    unsigned short* xpo = (unsigned short*)(xs + (size_t)wid * 16 * 108);

    const bf16x8* bfr = (const bf16x8*)Bp;
    #pragma unroll
    for (int mat = 0; mat < 2; ++mat) {
        unsigned short* outp = mat ? outR : outL;
        #pragma unroll
        for (int nf = 0; nf < 8; ++nf) {
            f32x4 acc = {0.f, 0.f, 0.f, 0.f};
            const int fi = (mat * 8 + nf) * 4;
            acc = __builtin_amdgcn_mfma_f32_16x16x32_bf16(a[0].v, bfr[(fi + 0) * 64 + lane], acc, 0, 0, 0);
            acc = __builtin_amdgcn_mfma_f32_16x16x32_bf16(a[1].v, bfr[(fi + 1) * 64 + lane], acc, 0, 0, 0);
            acc = __builtin_amdgcn_mfma_f32_16x16x32_bf16(a[2].v, bfr[(fi + 2) * 64 + lane], acc, 0, 0, 0);
            acc = __builtin_amdgcn_mfma_f32_16x16x32_bf16(a[3].v, bfr[(fi + 3) * 64 + lane], acc, 0, 0, 0);
            const int col = nf * 16 + row;
            #pragma unroll
            for (int j = 0; j < 4; ++j)
                xpo[(chunk * 4 + j) * 140 + col] = pack_bf1(acc[j]);
        }
        #pragma unroll
        for (int i = 0; i < 4; ++i) {
            const int r = i * 4 + chunk;
            const bf16x8 v = *(const bf16x8*)&xpo[r * 140 + row * 8];
            *(bf16x8*)(outp + (size_t)(rowblk + rowbase + r) * 128 + row * 8) = v;
        }
    }
}

// ---------------------------------------------------------------------------
// MFMA: xl2 = item_h[NI,128] @ c2_Wl + c2_bl -> bf16
// ---------------------------------------------------------------------------
__global__ __launch_bounds__(256)
void mfma_xl2(const float* __restrict__ X, const unsigned short* __restrict__ Bp,
              const float* __restrict__ bias, unsigned short* __restrict__ outp, int M)
{
    const int lane = threadIdx.x & 63;
    const int wt = (blockIdx.x * blockDim.x + threadIdx.x) >> 6;
    const int rowbase = wt * 16;
    if (rowbase >= M) return;
    const int chunk = lane >> 4;
    const float* rowp = X + (size_t)(rowbase + (lane & 15)) * 128;

    frag_u a[4];
    #pragma unroll
    for (int ks = 0; ks < 4; ++ks) {
        const int kb = ks * 32 + chunk * 8;
        const float4 p = *(const float4*)(rowp + kb);
        const float4 q = *(const float4*)(rowp + kb + 4);
        a[ks].u[0] = pack_bf2(p.x, p.y);
        a[ks].u[1] = pack_bf2(p.z, p.w);
        a[ks].u[2] = pack_bf2(q.x, q.y);
        a[ks].u[3] = pack_bf2(q.z, q.w);
    }

    const bf16x8* bfr = (const bf16x8*)Bp;
    #pragma unroll
    for (int nf = 0; nf < 8; ++nf) {
        f32x4 acc = {0.f, 0.f, 0.f, 0.f};
        const int fi = (16 + nf) * 4;   // mat 2
        acc = __builtin_amdgcn_mfma_f32_16x16x32_bf16(a[0].v, bfr[(fi + 0) * 64 + lane], acc, 0, 0, 0);
        acc = __builtin_amdgcn_mfma_f32_16x16x32_bf16(a[1].v, bfr[(fi + 1) * 64 + lane], acc, 0, 0, 0);
        acc = __builtin_amdgcn_mfma_f32_16x16x32_bf16(a[2].v, bfr[(fi + 2) * 64 + lane], acc, 0, 0, 0);
        acc = __builtin_amdgcn_mfma_f32_16x16x32_bf16(a[3].v, bfr[(fi + 3) * 64 + lane], acc, 0, 0, 0);
        const int col = nf * 16 + (lane & 15);
        const float bv = bias[col];
        #pragma unroll
        for (int j = 0; j < 4; ++j)
            outp[(size_t)(rowbase + chunk * 4 + j) * 128 + col] = pack_bf1(acc[j] + bv);
    }
}

// ---------------------------------------------------------------------------
// CSR build: hist + rank capture (atomics paid ONCE here)
// ---------------------------------------------------------------------------
__global__ void hist_rank(const int* __restrict__ src, const int* __restrict__ dst,
                          int* __restrict__ cntU, int* __restrict__ cntI,
                          int* __restrict__ rankU, int* __restrict__ rankI, int E)
{
    for (int i = blockIdx.x * blockDim.x + threadIdx.x; i < E;
         i += gridDim.x * blockDim.x) {
        rankU[i] = atomicAdd(&cntU[src[i]], 1);
        rankI[i] = atomicAdd(&cntI[dst[i]], 1);
    }
}

__global__ void scan_blocks(const int* __restrict__ in, int* __restrict__ out,
                            int* __restrict__ blockSums, int n)
{
    __shared__ int lds[256];
    const int tid = threadIdx.x;
    const int base = blockIdx.x * 1024 + tid * 4;
    int v[4];
    #pragma unroll
    for (int j = 0; j < 4; ++j) { int idx = base + j; v[j] = (idx < n) ? in[idx] : 0; }
    int t = v[0] + v[1] + v[2] + v[3];
    lds[tid] = t;
    __syncthreads();
    for (int off = 1; off < 256; off <<= 1) {
        int x = (tid >= off) ? lds[tid - off] : 0;
        __syncthreads();
        lds[tid] += x;
        __syncthreads();
    }
    int excl = lds[tid] - t;
    if (tid == 255 && blockSums) blockSums[blockIdx.x] = lds[255];
    int run = excl;
    #pragma unroll
    for (int j = 0; j < 4; ++j) {
        int idx = base + j;
        if (idx < n) out[idx] = run;
        run += v[j];
    }
}

__global__ void scan_add(int* __restrict__ out, const int* __restrict__ bss, int n)
{
    const int add = bss[blockIdx.x];
    const int base = blockIdx.x * 1024 + threadIdx.x * 4;
    #pragma unroll
    for (int j = 0; j < 4; ++j) { int idx = base + j; if (idx < n) out[idx] += add; }
}

// atomic-free scatter: pos = off[key] + rank (off read-only, L2-hot)
__global__ void scatter_ranked(const int* __restrict__ src, const int* __restrict__ dst,
                               const float* __restrict__ eattr,
                               const int* __restrict__ offU, const int* __restrict__ offI,
                               const int* __restrict__ rankU, const int* __restrict__ rankI,
                               int* __restrict__ sFund, uint4* __restrict__ sE1, int E)
{
    for (int i = blockIdx.x * blockDim.x + threadIdx.x; i < E;
         i += gridDim.x * blockDim.x) {
        const int s = src[i];
        const int d = dst[i];
        const float a0 = eattr[3 * (size_t)i];
        const float a1 = eattr[3 * (size_t)i + 1];
        const float a2 = eattr[3 * (size_t)i + 2];
        const int p1 = offI[d] + rankI[i];
        const int p2 = offU[s] + rankU[i];
        sE1[p1] = make_uint4((unsigned int)s, __float_as_uint(a0),
                             __float_as_uint(a1), __float_as_uint(a2));
        sFund[p2] = d;
    }
}

// ---------------------------------------------------------------------------
// conv1 fused: one wave per fund d; 8-deep gather pipeline.
// xr1 computed ON THE FLY from fund_x (rank-1): vr = fund_x[d]*wv + bb.
// ---------------------------------------------------------------------------
__device__ __forceinline__ void conv1_edge(uint4 e, unsigned int vbits, float2 vr,
                                           float2 av, float2 w0, float2 w1, float2 w2,
                                           float& acc0, float& acc1, float& s)
{
    const float2 vl = unpack_bf2(vbits);
    const float e0 = __uint_as_float(e.y);
    const float e1 = __uint_as_float(e.z);
    const float e2 = __uint_as_float(e.w);
    float h0 = vl.x + vr.x + e0 * w0.x + e1 * w1.x + e2 * w2.x;
    float h1 = vl.y + vr.y + e0 * w0.y + e1 * w1.y + e2 * w2.y;
    h0 = h0 > 0.f ? h0 : 0.2f * h0;
    h1 = h1 > 0.f ? h1 : 0.2f * h1;
    const float p = head_reduce(h0 * av.x + h1 * av.y);
    const float ex = __expf(p);
    acc0 = fmaf(ex, vl.x, acc0);
    acc1 = fmaf(ex, vl.y, acc1);
    s += ex;
}

__global__ void conv1_fused(const unsigned int* __restrict__ xl,
                            const float* __restrict__ fund_x,
                            const float* __restrict__ wvbb,
                            const int* __restrict__ offI, const int* __restrict__ cnt,
                            const uint4* __restrict__ sE,
                            const float* __restrict__ We, const float* __restrict__ att,
                            const float* __restrict__ bias,
                            float* __restrict__ outF, int ndst)
{
    const int tid = threadIdx.x;
    const int lane = tid & 63;
    const int wid = tid >> 6;
    const int d = blockIdx.x * 4 + wid;
    if (d >= ndst) return;

    const int ch = lane * 2;
    const float2 av = *(const float2*)(att + ch);
    const float2 w0 = *(const float2*)(We + ch);
    const float2 w1 = *(const float2*)(We + HC + ch);
    const float2 w2 = *(const float2*)(We + 2 * HC + ch);
    const float2 bv = *(const float2*)(bias + ch);

    // xr1 row on the fly
    const float fx = fund_x[d];
    const float2 wv = *(const float2*)(wvbb + ch);
    const float2 bb = *(const float2*)(wvbb + 128 + ch);
    const float2 vr = make_float2(fmaf(fx, wv.x, bb.x), fmaf(fx, wv.y, bb.y));

    const int start = offI[d];
    const int end = start + cnt[d];

    float acc0 = 0.f, acc1 = 0.f, s = 0.f;
    int pos = start;
    for (; pos + 8 <= end; pos += 8) {
        uint4 e[8];
        unsigned int v[8];
        #pragma unroll
        for (int j = 0; j < 8; ++j) e[j] = sE[pos + j];
        #pragma unroll
        for (int j = 0; j < 8; ++j) v[j] = xl[(size_t)e[j].x * 64 + lane];
        #pragma unroll
        for (int j = 0; j < 8; ++j)
            conv1_edge(e[j], v[j], vr, av, w0, w1, w2, acc0, acc1, s);
    }
    for (; pos + 4 <= end; pos += 4) {
        uint4 e[4];
        unsigned int v[4];
        #pragma unroll
        for (int j = 0; j < 4; ++j) e[j] = sE[pos + j];
        #pragma unroll
        for (int j = 0; j < 4; ++j) v[j] = xl[(size_t)e[j].x * 64 + lane];
        #pragma unroll
        for (int j = 0; j < 4; ++j)
            conv1_edge(e[j], v[j], vr, av, w0, w1, w2, acc0, acc1, s);
    }
    for (; pos < end; ++pos) {
        const uint4 e = sE[pos];
        const unsigned int v = xl[(size_t)e.x * 64 + lane];
        conv1_edge(e, v, vr, av, w0, w1, w2, acc0, acc1, s);
    }
    const float inv = 1.f / (s + 1e-16f);
    const float o0 = fmaxf(acc0 * inv + bv.x, 0.f);
    const float o1 = fmaxf(acc1 * inv + bv.y, 0.f);
    *(float2*)(outF + (size_t)d * HC + ch) = make_float2(o0, o1);
}

// ---------------------------------------------------------------------------
// conv2 + classifier fused: one wave per 16 users, FLATTENED edge stream.
// ---------------------------------------------------------------------------
__device__ __forceinline__ void conv2_edge(unsigned int vbits, float2 vr, float2 av,
                                           float& acc0, float& acc1, float& s)
{
    const float2 vl = unpack_bf2(vbits);
    float h0 = vl.x + vr.x;
    float h1 = vl.y + vr.y;
    h0 = h0 > 0.f ? h0 : 0.2f * h0;
    h1 = h1 > 0.f ? h1 : 0.2f * h1;
    const float p = head_reduce(h0 * av.x + h1 * av.y);
    const float ex = __expf(p);
    acc0 = fmaf(ex, vl.x, acc0);
    acc1 = fmaf(ex, vl.y, acc1);
    s += ex;
}

__global__ __launch_bounds__(256)
void conv2_cls(const unsigned int* __restrict__ xl2,
               const unsigned int* __restrict__ xr2,
               const int* __restrict__ offU, const int* __restrict__ cnt,
               const int* __restrict__ sFund,
               const float* __restrict__ att, const float* __restrict__ cbias,
               const unsigned short* __restrict__ Bp1,
               const float* __restrict__ b1, const float* __restrict__ W2,
               const float* __restrict__ b2,
               float* __restrict__ out, int nusr)
{
    __shared__ unsigned short xs[4][16][136];

    const int lane = threadIdx.x & 63;
    const int wid = threadIdx.x >> 6;
    const int wt = (blockIdx.x * blockDim.x + threadIdx.x) >> 6;
    const int u0 = wt * 16;
    if (u0 >= nusr) return;

    const int ch = lane * 2;
    const float2 av = *(const float2*)(att + ch);
    const float2 bv = *(const float2*)(cbias + ch);

    // lane-parallel offsets for this wave's 16 users (NU % 16 == 0)
    int so = 0, ctv = 0;
    if (lane < 16) {
        so = offU[u0 + lane];
        ctv = cnt[u0 + lane];
    }
    const int eo = so + ctv;   // bucket end per lane
    const int S = __builtin_amdgcn_readlane(so, 0);
    const int E = __builtin_amdgcn_readlane(eo, 15);

    int u = 0;
    int end_u = __builtin_amdgcn_readlane(eo, 0);
    unsigned int vrb_next = xr2[(size_t)(u0 + 1) * 64 + lane];
    float2 vr = unpack_bf2(xr2[(size_t)u0 * 64 + lane]);
    float acc0 = 0.f, acc1 = 0.f, s = 0.f;

    #define FINALIZE() {                                                        \
        const float inv = 1.f / (s + 1e-16f);                                   \
        *(unsigned int*)&xs[wid][u][ch] = pack_bf2(acc0 * inv + bv.x,           \
                                                   acc1 * inv + bv.y);          \
        acc0 = acc1 = s = 0.f;                                                  \
        ++u;                                                                    \
        if (u < 16) {                                                           \
            end_u = __builtin_amdgcn_readlane(eo, u);                           \
            vr = unpack_bf2(vrb_next);                                          \
            if (u + 1 < 16) vrb_next = xr2[(size_t)(u0 + u + 1) * 64 + lane];   \
        }                                                                       \
    }

    int pos = S;
    while (pos < E) {
        const int f0 = sFund[pos];
        const int f1 = (pos + 1 < E) ? sFund[pos + 1] : f0;
        const int f2 = (pos + 2 < E) ? sFund[pos + 2] : f0;
        const int f3 = (pos + 3 < E) ? sFund[pos + 3] : f0;
        const unsigned int v0 = xl2[(size_t)f0 * 64 + lane];
        const unsigned int v1 = xl2[(size_t)f1 * 64 + lane];
        const unsigned int v2 = xl2[(size_t)f2 * 64 + lane];
        const unsigned int v3 = xl2[(size_t)f3 * 64 + lane];

        while (pos == end_u) FINALIZE();
        conv2_edge(v0, vr, av, acc0, acc1, s);
        if (pos + 1 < E) {
            while (pos + 1 == end_u) FINALIZE();
            conv2_edge(v1, vr, av, acc0, acc1, s);
        }
        if (pos + 2 < E) {
            while (pos + 2 == end_u) FINALIZE();
            conv2_edge(v2, vr, av, acc0, acc1, s);
        }
        if (pos + 3 < E) {
            while (pos + 3 == end_u) FINALIZE();
            conv2_edge(v3, vr, av, acc0, acc1, s);
        }
        pos += 4;
    }
    while (u < 16) FINALIZE();
    #undef FINALIZE

    // --- phase 2: MLP via MFMA (A = 16 user rows, K=128) ---
    const int row = lane & 15;
    const int chunk = lane >> 4;
    bf16x8 a[4];
    #pragma unroll
    for (int ks = 0; ks < 4; ++ks)
        a[ks] = *(const bf16x8*)&xs[wid][row][ks * 32 + chunk * 8];

    const bf16x8* bfr = (const bf16x8*)Bp1;
    float racc[4] = {0.f, 0.f, 0.f, 0.f};
    #pragma unroll
    for (int g = 0; g < 4; ++g) {
        f32x4 acc = {0.f, 0.f, 0.f, 0.f};
        const int fi = g * 4;
        acc = __builtin_amdgcn_mfma_f32_16x16x32_bf16(a[0], bfr[(fi + 0) * 64 + lane], acc, 0, 0, 0);
        acc = __builtin_amdgcn_mfma_f32_16x16x32_bf16(a[1], bfr[(fi + 1) * 64 + lane], acc, 0, 0, 0);
        acc = __builtin_amdgcn_mfma_f32_16x16x32_bf16(a[2], bfr[(fi + 2) * 64 + lane], acc, 0, 0, 0);
        acc = __builtin_amdgcn_mfma_f32_16x16x32_bf16(a[3], bfr[(fi + 3) * 64 + lane], acc, 0, 0, 0);
        const int col = g * 16 + row;
        const float b1v = b1[col];
        const float w2v = W2[col];
        #pragma unroll
        for (int j = 0; j < 4; ++j)
            racc[j] = fmaf(fmaxf(acc[j] + b1v, 0.f), w2v, racc[j]);
    }
    #pragma unroll
    for (int j = 0; j < 4; ++j) {
        racc[j] += __shfl_xor(racc[j], 1, 16);
        racc[j] += __shfl_xor(racc[j], 2, 16);
        racc[j] += __shfl_xor(racc[j], 4, 16);
        racc[j] += __shfl_xor(racc[j], 8, 16);
    }
    if (row == 0) {
        const float b2v = b2[0];
        #pragma unroll
        for (int j = 0; j < 4; ++j) {
            const int r = u0 + chunk * 4 + j;
            if (r < nusr) out[r] = 1.f / (1.f + expf(-(racc[j] + b2v)));
        }
    }
}

// ---------------------------------------------------------------------------
extern "C" void kernel_launch(void* const* d_in, const int* in_sizes, int n_in,
                              void* d_out, int out_size, void* d_ws, size_t ws_size,
                              hipStream_t stream)
{
    const float* customer_x = (const float*)d_in[0];
    const float* fund_x     = (const float*)d_in[1];
    const float* edge_attr  = (const float*)d_in[2];
    const int*   edge_src   = (const int*)d_in[3];
    const int*   edge_dst   = (const int*)d_in[4];
    const float* user_W = (const float*)d_in[5];
    const float* user_b = (const float*)d_in[6];
    const float* item_W = (const float*)d_in[7];
    const float* item_b = (const float*)d_in[8];
    const float* c1_Wl  = (const float*)d_in[9];
    const float* c1_bl  = (const float*)d_in[10];
    const float* c1_Wr  = (const float*)d_in[11];
    const float* c1_br  = (const float*)d_in[12];
    const float* c1_We  = (const float*)d_in[13];
    const float* c1_att = (const float*)d_in[14];
    const float* c1_bias= (const float*)d_in[15];
    const float* c2_Wl  = (const float*)d_in[16];
    const float* c2_bl  = (const float*)d_in[17];
    const float* c2_Wr  = (const float*)d_in[18];
    const float* c2_br  = (const float*)d_in[19];
    const float* c2_att = (const float*)d_in[20];
    const float* c2_bias= (const float*)d_in[21];
    const float* cls_W1 = (const float*)d_in[22];
    const float* cls_b1 = (const float*)d_in[23];
    const float* cls_W2 = (const float*)d_in[24];
    const float* cls_b2 = (const float*)d_in[25];
    float* out = (float*)d_out;

    float* ws = (float*)d_ws;
    size_t off = 0;
    unsigned short* B1 = (unsigned short*)(ws + off); off += (size_t)NU * 64; // xl1 bf16
    unsigned short* B2 = (unsigned short*)(ws + off); off += (size_t)NU * 64; // xr2 bf16
    float* F = ws + off; off += (size_t)NI * HC;                              // item_h fp32
    unsigned short* G = (unsigned short*)(ws + off); off += (size_t)NI * 64;  // xl2 bf16
    int* cnt1  = (int*)(ws + off); off += NI;
    int* off1  = (int*)(ws + off); off += NI;
    int* cnt2  = (int*)(ws + off); off += NU;
    int* off2  = (int*)(ws + off); off += NU;
    int* bs    = (int*)(ws + off); off += 1024;
    int* bss   = (int*)(ws + off); off += 1024;
    uint4* sE1 = (uint4*)(ws + off); off += (size_t)NE * 4;
    int* sFund = (int*)(ws + off); off += NE;
    int* rankU = (int*)(ws + off); off += NE;
    int* rankI = (int*)(ws + off); off += NE;
    unsigned short* Bp = (unsigned short*)(ws + off); off += 12288 + 256;     // 96KB frags
    unsigned short* Bp1 = (unsigned short*)(ws + off); off += 4096 + 256;     // 16KB W1 frags
    float* wvbb = ws + off; off += 256;

    hipMemsetAsync(cnt1, 0, NI * sizeof(int), stream);
    hipMemsetAsync(cnt2, 0, NU * sizeof(int), stream);

    // CSR build: rank-capturing histogram -> scan -> atomic-free scatter
    hist_rank<<<1024, 256, 0, stream>>>(edge_src, edge_dst, cnt2, cnt1,
                                        rankU, rankI, NE);
    const int nb1 = (NI + 1023) / 1024;
    const int nb2 = (NU + 1023) / 1024;
    scan_blocks<<<nb1, 256, 0, stream>>>(cnt1, off1, bs, NI);
    scan_blocks<<<1,   256, 0, stream>>>(bs, bss, nullptr, nb1);
    scan_add<<<nb1, 256, 0, stream>>>(off1, bss, NI);
    scan_blocks<<<nb2, 256, 0, stream>>>(cnt2, off2, bs, NU);
    scan_blocks<<<1,   256, 0, stream>>>(bs, bss, nullptr, nb2);
    scan_add<<<nb2, 256, 0, stream>>>(off2, bss, NU);
    scatter_ranked<<<2048, 256, 0, stream>>>(edge_src, edge_dst, edge_attr,
                                             off2, off1, rankU, rankI,
                                             sFund, sE1, NE);

    // weight prep
    wprep<<<192, 256, 0, stream>>>(user_W, user_b, c1_Wl, c1_bl,
                                   c2_Wr, c2_br, c2_Wl, Bp);
    w1prep<<<32, 256, 0, stream>>>(cls_W1, Bp1);
    wvbb_prep<<<1, 128, 0, stream>>>(item_W, item_b, c1_Wr, c1_br, wvbb);

    // xl1 & xr2 in one MFMA pass over customer_x (32 rows/block, 128 thr)
    mfma_user<<<NU / 32, 128, 0, stream>>>(customer_x, Bp, B1, B2, NU);

    // conv1: customer -> fund (+bias+relu), xr1 on-the-fly, fp32 out F
    conv1_fused<<<NI / 4, 256, 0, stream>>>((const unsigned int*)B1, fund_x, wvbb,
                                            off1, cnt1, sE1,
                                            c1_We, c1_att, c1_bias, F, NI);

    // xl2 = item_h @ c2_Wl + c2_bl (bf16)
    mfma_xl2<<<(NI / 16 + 3) / 4, 256, 0, stream>>>(F, Bp, c2_bl, G, NI);

    // conv2 + classifier fused: one wave per 16 users
    const int waves2 = (NU + 15) / 16;             // 31250
    conv2_cls<<<(waves2 + 3) / 4, 256, 0, stream>>>(
        (const unsigned int*)G, (const unsigned int*)B2, off2, cnt2, sFund,
        c2_att, c2_bias, Bp1, cls_b1, cls_W2, cls_b2, out, NU);
}

// Round 18
// 535.332 us; speedup vs baseline: 1.0087x; 1.0087x over previous
//
#include <hip/hip_runtime.h>
#include <cstdint>
#include <cstddef>

#define NU 500000
#define NI 50000
#define NE 1000000
#define HC 128   // H*C
#define NH 4

typedef __attribute__((ext_vector_type(8))) short bf16x8;
typedef __attribute__((ext_vector_type(4))) float f32x4;

union frag_u { bf16x8 v; unsigned int u[4]; };

// bf16 pack/unpack (RNE)
__device__ __forceinline__ unsigned int pack_bf2(float x, float y) {
    unsigned int r;
    asm("v_cvt_pk_bf16_f32 %0, %1, %2" : "=v"(r) : "v"(x), "v"(y));
    return r;
}
__device__ __forceinline__ float2 unpack_bf2(unsigned int v) {
    return make_float2(__uint_as_float(v << 16),
                       __uint_as_float(v & 0xffff0000u));
}
__device__ __forceinline__ unsigned short pack_bf1(float x) {
    unsigned int b = __float_as_uint(x);
    b += 0x7fffu + ((b >> 16) & 1u);
    return (unsigned short)(b >> 16);
}

__device__ __forceinline__ float head_reduce(float p) {
    p += __shfl_xor(p, 8, 16);
    p += __shfl_xor(p, 4, 16);
    p += __shfl_xor(p, 2, 16);
    p += __shfl_xor(p, 1, 16);
    return p;
}

// ---------------------------------------------------------------------------
// Weight prep: Bp holds 3 matrices in MFMA fragment order, bf16.
// ---------------------------------------------------------------------------
__global__ void wprep(const float* __restrict__ user_W, const float* __restrict__ user_b,
                      const float* __restrict__ c1_Wl, const float* __restrict__ c1_bl,
                      const float* __restrict__ c2_Wr, const float* __restrict__ c2_br,
                      const float* __restrict__ c2_Wl, unsigned short* __restrict__ Bp)
{
    const int t = blockIdx.x * 256 + threadIdx.x;   // 0..49151
    const int mat = t >> 14;
    const int k = (t >> 7) & 127;
    const int n = t & 127;
    float val = 0.f;
    if (mat == 2) {
        val = c2_Wl[k * 128 + n];
    } else {
        const float* W2 = mat ? c2_Wr : c1_Wl;
        if (k < 101) {
            for (int q = 0; q < 32; ++q) val = fmaf(user_W[k * 32 + q], W2[q * 128 + n], val);
        } else if (k == 101) {
            for (int q = 0; q < 32; ++q) val = fmaf(user_b[q], W2[q * 128 + n], val);
            val += (mat ? c2_br : c1_bl)[n];
        }
    }
    const int fi = (mat * 8 + (n >> 4)) * 4 + (k >> 5);
    const int lane_ = (n & 15) + ((k >> 3) & 3) * 16;
    Bp[(size_t)fi * 512 + lane_ * 8 + (k & 7)] = pack_bf1(val);
}

// ---------------------------------------------------------------------------
// W1 (classifier, 128x64) -> fragment order, 16 frags
// ---------------------------------------------------------------------------
__global__ void w1prep(const float* __restrict__ W1, unsigned short* __restrict__ Bp1)
{
    const int t = blockIdx.x * 256 + threadIdx.x;   // 0..8191
    const int k = t >> 6;
    const int n = t & 63;
    const float val = W1[k * 64 + n];
    const int fi = (n >> 4) * 4 + (k >> 5);
    const int lane_ = (n & 15) + ((k >> 3) & 3) * 16;
    Bp1[(size_t)fi * 512 + lane_ * 8 + (k & 7)] = pack_bf1(val);
}

// ---------------------------------------------------------------------------
// xr1 rank-1 weights: wv[j] = item_W@c1_Wr, bb[j] = item_b@c1_Wr + c1_br
// ---------------------------------------------------------------------------
__global__ void wvbb_prep(const float* __restrict__ item_W, const float* __restrict__ item_b,
                          const float* __restrict__ c1_Wr, const float* __restrict__ c1_br,
                          float* __restrict__ wvbb)
{
    const int j = threadIdx.x;
    if (j >= 128) return;
    float wv = 0.f, bb = 0.f;
    for (int q = 0; q < 32; ++q) {
        wv = fmaf(item_W[q], c1_Wr[q * 128 + j], wv);
        bb = fmaf(item_b[q], c1_Wr[q * 128 + j], bb);
    }
    wvbb[j] = wv;
    wvbb[128 + j] = bb + c1_br[j];
}

// ---------------------------------------------------------------------------
// HYBRID: blocks [0, nub) run the MFMA user projection (round-15 config,
// 256 thr / 64 rows / pitch-140 xpo, known-good 154us); blocks [nub, ...)
// run the atomic-free edge scatter. The two are data-independent; fusing
// them lets scatter fill CU slots the 41%-occupancy MFMA leaves idle.
// ---------------------------------------------------------------------------
__global__ __launch_bounds__(256)
void mfma_user_scatter(const float* __restrict__ cx, const unsigned short* __restrict__ Bp,
                       unsigned short* __restrict__ outL, unsigned short* __restrict__ outR,
                       int M, int nub,
                       const int* __restrict__ src, const int* __restrict__ dst,
                       const float* __restrict__ eattr,
                       const int* __restrict__ offU, const int* __restrict__ offI,
                       const int* __restrict__ rankU, const int* __restrict__ rankI,
                       int* __restrict__ sFund, uint4* __restrict__ sE1, int E, int nscat)
{
    __shared__ float xs[64 * 108];   // 27648 B

    if (blockIdx.x >= nub) {
        // ---- scatter role ----
        const int bid = blockIdx.x - nub;
        for (int i = bid * 256 + threadIdx.x; i < E; i += nscat * 256) {
            const int s = src[i];
            const int d = dst[i];
            const float a0 = eattr[3 * (size_t)i];
            const float a1 = eattr[3 * (size_t)i + 1];
            const float a2 = eattr[3 * (size_t)i + 2];
            const int p1 = offI[d] + rankI[i];
            const int p2 = offU[s] + rankU[i];
            sE1[p1] = make_uint4((unsigned int)s, __float_as_uint(a0),
                                 __float_as_uint(a1), __float_as_uint(a2));
            sFund[p2] = d;
        }
        return;
    }

    // ---- MFMA projection role ----
    const int tid = threadIdx.x;
    const int lane = tid & 63;
    const int wid = tid >> 6;
    const int rowblk = blockIdx.x * 64;
    const int rows = min(64, M - rowblk);

    const float* srcp = cx + (size_t)rowblk * 101;
    const int total = rows * 101;
    for (int i = tid; i < total; i += 256) {
        const int r = i / 101;
        const int c = i - r * 101;
        xs[r * 108 + c] = srcp[i];
    }
    __syncthreads();

    const int rowbase = wid * 16;
    if (rowbase >= rows) return;
    const int row = lane & 15;
    const int chunk = lane >> 4;
    const float* rowp = xs + (rowbase + row) * 108;

    frag_u a[4];
    #pragma unroll
    for (int ks = 0; ks < 3; ++ks) {
        const int kb = ks * 32 + chunk * 8;
        const float4 p = *(const float4*)(rowp + kb);
        const float4 q = *(const float4*)(rowp + kb + 4);
        a[ks].u[0] = pack_bf2(p.x, p.y);
        a[ks].u[1] = pack_bf2(p.z, p.w);
        a[ks].u[2] = pack_bf2(q.x, q.y);
        a[ks].u[3] = pack_bf2(q.z, q.w);
    }
    {   // kstep 3: k 96..100 real, k=101 -> 1.0 (bias row), rest 0
        float v0 = 0.f, v1 = 0.f, v2 = 0.f, v3 = 0.f, v4 = 0.f, v5 = 0.f;
        if (chunk == 0) {
            const float4 p = *(const float4*)(rowp + 96);
            v0 = p.x; v1 = p.y; v2 = p.z; v3 = p.w;
            v4 = rowp[100];
            v5 = 1.0f;
        }
        a[3].u[0] = pack_bf2(v0, v1);
        a[3].u[1] = pack_bf2(v2, v3);
        a[3].u[2] = pack_bf2(v4, v5);
        a[3].u[3] = 0u;
    }

    unsigned short* xpo = (unsigned short*)(xs + (size_t)wid * 16 * 108);

    const bf16x8* bfr = (const bf16x8*)Bp;
    #pragma unroll
    for (int mat = 0; mat < 2; ++mat) {
        unsigned short* outp = mat ? outR : outL;
        #pragma unroll
        for (int nf = 0; nf < 8; ++nf) {
            f32x4 acc = {0.f, 0.f, 0.f, 0.f};
            const int fi = (mat * 8 + nf) * 4;
            acc = __builtin_amdgcn_mfma_f32_16x16x32_bf16(a[0].v, bfr[(fi + 0) * 64 + lane], acc, 0, 0, 0);
            acc = __builtin_amdgcn_mfma_f32_16x16x32_bf16(a[1].v, bfr[(fi + 1) * 64 + lane], acc, 0, 0, 0);
            acc = __builtin_amdgcn_mfma_f32_16x16x32_bf16(a[2].v, bfr[(fi + 2) * 64 + lane], acc, 0, 0, 0);
            acc = __builtin_amdgcn_mfma_f32_16x16x32_bf16(a[3].v, bfr[(fi + 3) * 64 + lane], acc, 0, 0, 0);
            const int col = nf * 16 + row;
            #pragma unroll
            for (int j = 0; j < 4; ++j)
                xpo[(chunk * 4 + j) * 140 + col] = pack_bf1(acc[j]);
        }
        #pragma unroll
        for (int i = 0; i < 4; ++i) {
            const int r = i * 4 + chunk;
            const bf16x8 v = *(const bf16x8*)&xpo[r * 140 + row * 8];
            *(bf16x8*)(outp + (size_t)(rowblk + rowbase + r) * 128 + row * 8) = v;
        }
    }
}

// ---------------------------------------------------------------------------
// MFMA: xl2 = item_h[NI,128] @ c2_Wl + c2_bl -> bf16
// ---------------------------------------------------------------------------
__global__ __launch_bounds__(256)
void mfma_xl2(const float* __restrict__ X, const unsigned short* __restrict__ Bp,
              const float* __restrict__ bias, unsigned short* __restrict__ outp, int M)
{
    const int lane = threadIdx.x & 63;
    const int wt = (blockIdx.x * blockDim.x + threadIdx.x) >> 6;
    const int rowbase = wt * 16;
    if (rowbase >= M) return;
    const int chunk = lane >> 4;
    const float* rowp = X + (size_t)(rowbase + (lane & 15)) * 128;

    frag_u a[4];
    #pragma unroll
    for (int ks = 0; ks < 4; ++ks) {
        const int kb = ks * 32 + chunk * 8;
        const float4 p = *(const float4*)(rowp + kb);
        const float4 q = *(const float4*)(rowp + kb + 4);
        a[ks].u[0] = pack_bf2(p.x, p.y);
        a[ks].u[1] = pack_bf2(p.z, p.w);
        a[ks].u[2] = pack_bf2(q.x, q.y);
        a[ks].u[3] = pack_bf2(q.z, q.w);
    }

    const bf16x8* bfr = (const bf16x8*)Bp;
    #pragma unroll
    for (int nf = 0; nf < 8; ++nf) {
        f32x4 acc = {0.f, 0.f, 0.f, 0.f};
        const int fi = (16 + nf) * 4;   // mat 2
        acc = __builtin_amdgcn_mfma_f32_16x16x32_bf16(a[0].v, bfr[(fi + 0) * 64 + lane], acc, 0, 0, 0);
        acc = __builtin_amdgcn_mfma_f32_16x16x32_bf16(a[1].v, bfr[(fi + 1) * 64 + lane], acc, 0, 0, 0);
        acc = __builtin_amdgcn_mfma_f32_16x16x32_bf16(a[2].v, bfr[(fi + 2) * 64 + lane], acc, 0, 0, 0);
        acc = __builtin_amdgcn_mfma_f32_16x16x32_bf16(a[3].v, bfr[(fi + 3) * 64 + lane], acc, 0, 0, 0);
        const int col = nf * 16 + (lane & 15);
        const float bv = bias[col];
        #pragma unroll
        for (int j = 0; j < 4; ++j)
            outp[(size_t)(rowbase + chunk * 4 + j) * 128 + col] = pack_bf1(acc[j] + bv);
    }
}

// ---------------------------------------------------------------------------
// CSR build: hist + rank capture (atomics paid ONCE here)
// ---------------------------------------------------------------------------
__global__ void hist_rank(const int* __restrict__ src, const int* __restrict__ dst,
                          int* __restrict__ cntU, int* __restrict__ cntI,
                          int* __restrict__ rankU, int* __restrict__ rankI, int E)
{
    for (int i = blockIdx.x * blockDim.x + threadIdx.x; i < E;
         i += gridDim.x * blockDim.x) {
        rankU[i] = atomicAdd(&cntU[src[i]], 1);
        rankI[i] = atomicAdd(&cntI[dst[i]], 1);
    }
}

__global__ void scan_blocks(const int* __restrict__ in, int* __restrict__ out,
                            int* __restrict__ blockSums, int n)
{
    __shared__ int lds[256];
    const int tid = threadIdx.x;
    const int base = blockIdx.x * 1024 + tid * 4;
    int v[4];
    #pragma unroll
    for (int j = 0; j < 4; ++j) { int idx = base + j; v[j] = (idx < n) ? in[idx] : 0; }
    int t = v[0] + v[1] + v[2] + v[3];
    lds[tid] = t;
    __syncthreads();
    for (int off = 1; off < 256; off <<= 1) {
        int x = (tid >= off) ? lds[tid - off] : 0;
        __syncthreads();
        lds[tid] += x;
        __syncthreads();
    }
    int excl = lds[tid] - t;
    if (tid == 255 && blockSums) blockSums[blockIdx.x] = lds[255];
    int run = excl;
    #pragma unroll
    for (int j = 0; j < 4; ++j) {
        int idx = base + j;
        if (idx < n) out[idx] = run;
        run += v[j];
    }
}

__global__ void scan_add(int* __restrict__ out, const int* __restrict__ bss, int n)
{
    const int add = bss[blockIdx.x];
    const int base = blockIdx.x * 1024 + threadIdx.x * 4;
    #pragma unroll
    for (int j = 0; j < 4; ++j) { int idx = base + j; if (idx < n) out[idx] += add; }
}

// ---------------------------------------------------------------------------
// conv1 fused: one wave per fund d; 8-deep gather pipeline.
// xr1 computed ON THE FLY from fund_x (rank-1): vr = fund_x[d]*wv + bb.
// ---------------------------------------------------------------------------
__device__ __forceinline__ void conv1_edge(uint4 e, unsigned int vbits, float2 vr,
                                           float2 av, float2 w0, float2 w1, float2 w2,
                                           float& acc0, float& acc1, float& s)
{
    const float2 vl = unpack_bf2(vbits);
    const float e0 = __uint_as_float(e.y);
    const float e1 = __uint_as_float(e.z);
    const float e2 = __uint_as_float(e.w);
    float h0 = vl.x + vr.x + e0 * w0.x + e1 * w1.x + e2 * w2.x;
    float h1 = vl.y + vr.y + e0 * w0.y + e1 * w1.y + e2 * w2.y;
    h0 = h0 > 0.f ? h0 : 0.2f * h0;
    h1 = h1 > 0.f ? h1 : 0.2f * h1;
    const float p = head_reduce(h0 * av.x + h1 * av.y);
    const float ex = __expf(p);
    acc0 = fmaf(ex, vl.x, acc0);
    acc1 = fmaf(ex, vl.y, acc1);
    s += ex;
}

__global__ void conv1_fused(const unsigned int* __restrict__ xl,
                            const float* __restrict__ fund_x,
                            const float* __restrict__ wvbb,
                            const int* __restrict__ offI, const int* __restrict__ cnt,
                            const uint4* __restrict__ sE,
                            const float* __restrict__ We, const float* __restrict__ att,
                            const float* __restrict__ bias,
                            float* __restrict__ outF, int ndst)
{
    const int tid = threadIdx.x;
    const int lane = tid & 63;
    const int wid = tid >> 6;
    const int d = blockIdx.x * 4 + wid;
    if (d >= ndst) return;

    const int ch = lane * 2;
    const float2 av = *(const float2*)(att + ch);
    const float2 w0 = *(const float2*)(We + ch);
    const float2 w1 = *(const float2*)(We + HC + ch);
    const float2 w2 = *(const float2*)(We + 2 * HC + ch);
    const float2 bv = *(const float2*)(bias + ch);

    // xr1 row on the fly
    const float fx = fund_x[d];
    const float2 wv = *(const float2*)(wvbb + ch);
    const float2 bb = *(const float2*)(wvbb + 128 + ch);
    const float2 vr = make_float2(fmaf(fx, wv.x, bb.x), fmaf(fx, wv.y, bb.y));

    const int start = offI[d];
    const int end = start + cnt[d];

    float acc0 = 0.f, acc1 = 0.f, s = 0.f;
    int pos = start;
    for (; pos + 8 <= end; pos += 8) {
        uint4 e[8];
        unsigned int v[8];
        #pragma unroll
        for (int j = 0; j < 8; ++j) e[j] = sE[pos + j];
        #pragma unroll
        for (int j = 0; j < 8; ++j) v[j] = xl[(size_t)e[j].x * 64 + lane];
        #pragma unroll
        for (int j = 0; j < 8; ++j)
            conv1_edge(e[j], v[j], vr, av, w0, w1, w2, acc0, acc1, s);
    }
    for (; pos + 4 <= end; pos += 4) {
        uint4 e[4];
        unsigned int v[4];
        #pragma unroll
        for (int j = 0; j < 4; ++j) e[j] = sE[pos + j];
        #pragma unroll
        for (int j = 0; j < 4; ++j) v[j] = xl[(size_t)e[j].x * 64 + lane];
        #pragma unroll
        for (int j = 0; j < 4; ++j)
            conv1_edge(e[j], v[j], vr, av, w0, w1, w2, acc0, acc1, s);
    }
    for (; pos < end; ++pos) {
        const uint4 e = sE[pos];
        const unsigned int v = xl[(size_t)e.x * 64 + lane];
        conv1_edge(e, v, vr, av, w0, w1, w2, acc0, acc1, s);
    }
    const float inv = 1.f / (s + 1e-16f);
    const float o0 = fmaxf(acc0 * inv + bv.x, 0.f);
    const float o1 = fmaxf(acc1 * inv + bv.y, 0.f);
    *(float2*)(outF + (size_t)d * HC + ch) = make_float2(o0, o1);
}

// ---------------------------------------------------------------------------
// conv2 + classifier fused: one wave per 16 users, FLATTENED edge stream.
// ---------------------------------------------------------------------------
__device__ __forceinline__ void conv2_edge(unsigned int vbits, float2 vr, float2 av,
                                           float& acc0, float& acc1, float& s)
{
    const float2 vl = unpack_bf2(vbits);
    float h0 = vl.x + vr.x;
    float h1 = vl.y + vr.y;
    h0 = h0 > 0.f ? h0 : 0.2f * h0;
    h1 = h1 > 0.f ? h1 : 0.2f * h1;
    const float p = head_reduce(h0 * av.x + h1 * av.y);
    const float ex = __expf(p);
    acc0 = fmaf(ex, vl.x, acc0);
    acc1 = fmaf(ex, vl.y, acc1);
    s += ex;
}

__global__ __launch_bounds__(256)
void conv2_cls(const unsigned int* __restrict__ xl2,
               const unsigned int* __restrict__ xr2,
               const int* __restrict__ offU, const int* __restrict__ cnt,
               const int* __restrict__ sFund,
               const float* __restrict__ att, const float* __restrict__ cbias,
               const unsigned short* __restrict__ Bp1,
               const float* __restrict__ b1, const float* __restrict__ W2,
               const float* __restrict__ b2,
               float* __restrict__ out, int nusr)
{
    __shared__ unsigned short xs[4][16][136];

    const int lane = threadIdx.x & 63;
    const int wid = threadIdx.x >> 6;
    const int wt = (blockIdx.x * blockDim.x + threadIdx.x) >> 6;
    const int u0 = wt * 16;
    if (u0 >= nusr) return;

    const int ch = lane * 2;
    const float2 av = *(const float2*)(att + ch);
    const float2 bv = *(const float2*)(cbias + ch);

    // lane-parallel offsets for this wave's 16 users (NU % 16 == 0)
    int so = 0, ctv = 0;
    if (lane < 16) {
        so = offU[u0 + lane];
        ctv = cnt[u0 + lane];
    }
    const int eo = so + ctv;   // bucket end per lane
    const int S = __builtin_amdgcn_readlane(so, 0);
    const int E = __builtin_amdgcn_readlane(eo, 15);

    int u = 0;
    int end_u = __builtin_amdgcn_readlane(eo, 0);
    unsigned int vrb_next = xr2[(size_t)(u0 + 1) * 64 + lane];
    float2 vr = unpack_bf2(xr2[(size_t)u0 * 64 + lane]);
    float acc0 = 0.f, acc1 = 0.f, s = 0.f;

    #define FINALIZE() {                                                        \
        const float inv = 1.f / (s + 1e-16f);                                   \
        *(unsigned int*)&xs[wid][u][ch] = pack_bf2(acc0 * inv + bv.x,           \
                                                   acc1 * inv + bv.y);          \
        acc0 = acc1 = s = 0.f;                                                  \
        ++u;                                                                    \
        if (u < 16) {                                                           \
            end_u = __builtin_amdgcn_readlane(eo, u);                           \
            vr = unpack_bf2(vrb_next);                                          \
            if (u + 1 < 16) vrb_next = xr2[(size_t)(u0 + u + 1) * 64 + lane];   \
        }                                                                       \
    }

    int pos = S;
    while (pos < E) {
        const int f0 = sFund[pos];
        const int f1 = (pos + 1 < E) ? sFund[pos + 1] : f0;
        const int f2 = (pos + 2 < E) ? sFund[pos + 2] : f0;
        const int f3 = (pos + 3 < E) ? sFund[pos + 3] : f0;
        const unsigned int v0 = xl2[(size_t)f0 * 64 + lane];
        const unsigned int v1 = xl2[(size_t)f1 * 64 + lane];
        const unsigned int v2 = xl2[(size_t)f2 * 64 + lane];
        const unsigned int v3 = xl2[(size_t)f3 * 64 + lane];

        while (pos == end_u) FINALIZE();
        conv2_edge(v0, vr, av, acc0, acc1, s);
        if (pos + 1 < E) {
            while (pos + 1 == end_u) FINALIZE();
            conv2_edge(v1, vr, av, acc0, acc1, s);
        }
        if (pos + 2 < E) {
            while (pos + 2 == end_u) FINALIZE();
            conv2_edge(v2, vr, av, acc0, acc1, s);
        }
        if (pos + 3 < E) {
            while (pos + 3 == end_u) FINALIZE();
            conv2_edge(v3, vr, av, acc0, acc1, s);
        }
        pos += 4;
    }
    while (u < 16) FINALIZE();
    #undef FINALIZE

    // --- phase 2: MLP via MFMA (A = 16 user rows, K=128) ---
    const int row = lane & 15;
    const int chunk = lane >> 4;
    bf16x8 a[4];
    #pragma unroll
    for (int ks = 0; ks < 4; ++ks)
        a[ks] = *(const bf16x8*)&xs[wid][row][ks * 32 + chunk * 8];

    const bf16x8* bfr = (const bf16x8*)Bp1;
    float racc[4] = {0.f, 0.f, 0.f, 0.f};
    #pragma unroll
    for (int g = 0; g < 4; ++g) {
        f32x4 acc = {0.f, 0.f, 0.f, 0.f};
        const int fi = g * 4;
        acc = __builtin_amdgcn_mfma_f32_16x16x32_bf16(a[0], bfr[(fi + 0) * 64 + lane], acc, 0, 0, 0);
        acc = __builtin_amdgcn_mfma_f32_16x16x32_bf16(a[1], bfr[(fi + 1) * 64 + lane], acc, 0, 0, 0);
        acc = __builtin_amdgcn_mfma_f32_16x16x32_bf16(a[2], bfr[(fi + 2) * 64 + lane], acc, 0, 0, 0);
        acc = __builtin_amdgcn_mfma_f32_16x16x32_bf16(a[3], bfr[(fi + 3) * 64 + lane], acc, 0, 0, 0);
        const int col = g * 16 + row;
        const float b1v = b1[col];
        const float w2v = W2[col];
        #pragma unroll
        for (int j = 0; j < 4; ++j)
            racc[j] = fmaf(fmaxf(acc[j] + b1v, 0.f), w2v, racc[j]);
    }
    #pragma unroll
    for (int j = 0; j < 4; ++j) {
        racc[j] += __shfl_xor(racc[j], 1, 16);
        racc[j] += __shfl_xor(racc[j], 2, 16);
        racc[j] += __shfl_xor(racc[j], 4, 16);
        racc[j] += __shfl_xor(racc[j], 8, 16);
    }
    if (row == 0) {
        const float b2v = b2[0];
        #pragma unroll
        for (int j = 0; j < 4; ++j) {
            const int r = u0 + chunk * 4 + j;
            if (r < nusr) out[r] = 1.f / (1.f + expf(-(racc[j] + b2v)));
        }
    }
}

// ---------------------------------------------------------------------------
extern "C" void kernel_launch(void* const* d_in, const int* in_sizes, int n_in,
                              void* d_out, int out_size, void* d_ws, size_t ws_size,
                              hipStream_t stream)
{
    const float* customer_x = (const float*)d_in[0];
    const float* fund_x     = (const float*)d_in[1];
    const float* edge_attr  = (const float*)d_in[2];
    const int*   edge_src   = (const int*)d_in[3];
    const int*   edge_dst   = (const int*)d_in[4];
    const float* user_W = (const float*)d_in[5];
    const float* user_b = (const float*)d_in[6];
    const float* item_W = (const float*)d_in[7];
    const float* item_b = (const float*)d_in[8];
    const float* c1_Wl  = (const float*)d_in[9];
    const float* c1_bl  = (const float*)d_in[10];
    const float* c1_Wr  = (const float*)d_in[11];
    const float* c1_br  = (const float*)d_in[12];
    const float* c1_We  = (const float*)d_in[13];
    const float* c1_att = (const float*)d_in[14];
    const float* c1_bias= (const float*)d_in[15];
    const float* c2_Wl  = (const float*)d_in[16];
    const float* c2_bl  = (const float*)d_in[17];
    const float* c2_Wr  = (const float*)d_in[18];
    const float* c2_br  = (const float*)d_in[19];
    const float* c2_att = (const float*)d_in[20];
    const float* c2_bias= (const float*)d_in[21];
    const float* cls_W1 = (const float*)d_in[22];
    const float* cls_b1 = (const float*)d_in[23];
    const float* cls_W2 = (const float*)d_in[24];
    const float* cls_b2 = (const float*)d_in[25];
    float* out = (float*)d_out;

    float* ws = (float*)d_ws;
    size_t off = 0;
    unsigned short* B1 = (unsigned short*)(ws + off); off += (size_t)NU * 64; // xl1 bf16
    unsigned short* B2 = (unsigned short*)(ws + off); off += (size_t)NU * 64; // xr2 bf16
    float* F = ws + off; off += (size_t)NI * HC;                              // item_h fp32
    unsigned short* G = (unsigned short*)(ws + off); off += (size_t)NI * 64;  // xl2 bf16
    int* cnt1  = (int*)(ws + off); off += NI;
    int* off1  = (int*)(ws + off); off += NI;
    int* cnt2  = (int*)(ws + off); off += NU;
    int* off2  = (int*)(ws + off); off += NU;
    int* bs    = (int*)(ws + off); off += 1024;
    int* bss   = (int*)(ws + off); off += 1024;
    uint4* sE1 = (uint4*)(ws + off); off += (size_t)NE * 4;
    int* sFund = (int*)(ws + off); off += NE;
    int* rankU = (int*)(ws + off); off += NE;
    int* rankI = (int*)(ws + off); off += NE;
    unsigned short* Bp = (unsigned short*)(ws + off); off += 12288 + 256;     // 96KB frags
    unsigned short* Bp1 = (unsigned short*)(ws + off); off += 4096 + 256;     // 16KB W1 frags
    float* wvbb = ws + off; off += 256;

    hipMemsetAsync(cnt1, 0, NI * sizeof(int), stream);
    hipMemsetAsync(cnt2, 0, NU * sizeof(int), stream);

    // CSR build: rank-capturing histogram -> scan
    hist_rank<<<1024, 256, 0, stream>>>(edge_src, edge_dst, cnt2, cnt1,
                                        rankU, rankI, NE);
    const int nb1 = (NI + 1023) / 1024;
    const int nb2 = (NU + 1023) / 1024;
    scan_blocks<<<nb1, 256, 0, stream>>>(cnt1, off1, bs, NI);
    scan_blocks<<<1,   256, 0, stream>>>(bs, bss, nullptr, nb1);
    scan_add<<<nb1, 256, 0, stream>>>(off1, bss, NI);
    scan_blocks<<<nb2, 256, 0, stream>>>(cnt2, off2, bs, NU);
    scan_blocks<<<1,   256, 0, stream>>>(bs, bss, nullptr, nb2);
    scan_add<<<nb2, 256, 0, stream>>>(off2, bss, NU);

    // weight prep
    wprep<<<192, 256, 0, stream>>>(user_W, user_b, c1_Wl, c1_bl,
                                   c2_Wr, c2_br, c2_Wl, Bp);
    w1prep<<<32, 256, 0, stream>>>(cls_W1, Bp1);
    wvbb_prep<<<1, 128, 0, stream>>>(item_W, item_b, c1_Wr, c1_br, wvbb);

    // HYBRID: MFMA user projection (blocks 0..nub) + edge scatter (rest)
    const int nub = (NU + 63) / 64;   // 7813
    const int nscat = 2048;
    mfma_user_scatter<<<nub + nscat, 256, 0, stream>>>(
        customer_x, Bp, B1, B2, NU, nub,
        edge_src, edge_dst, edge_attr, off2, off1, rankU, rankI,
        sFund, sE1, NE, nscat);

    // conv1: customer -> fund (+bias+relu), xr1 on-the-fly, fp32 out F
    conv1_fused<<<NI / 4, 256, 0, stream>>>((const unsigned int*)B1, fund_x, wvbb,
                                            off1, cnt1, sE1,
                                            c1_We, c1_att, c1_bias, F, NI);

    // xl2 = item_h @ c2_Wl + c2_bl (bf16)
    mfma_xl2<<<(NI / 16 + 3) / 4, 256, 0, stream>>>(F, Bp, c2_bl, G, NI);

    // conv2 + classifier fused: one wave per 16 users
    const int waves2 = (NU + 15) / 16;             // 31250
    conv2_cls<<<(waves2 + 3) / 4, 256, 0, stream>>>(
        (const unsigned int*)G, (const unsigned int*)B2, off2, cnt2, sFund,
        c2_att, c2_bias, Bp1, cls_b1, cls_W2, cls_b2, out, NU);
}

// Round 19
// 531.054 us; speedup vs baseline: 1.0169x; 1.0081x over previous
//
#include <hip/hip_runtime.h>
#include <cstdint>
#include <cstddef>

#define NU 500000
#define NI 50000
#define NE 1000000
#define HC 128   // H*C
#define NH 4

typedef __attribute__((ext_vector_type(8))) short bf16x8;
typedef __attribute__((ext_vector_type(4))) float f32x4;

union frag_u { bf16x8 v; unsigned int u[4]; };

// bf16 pack/unpack (RNE)
__device__ __forceinline__ unsigned int pack_bf2(float x, float y) {
    unsigned int r;
    asm("v_cvt_pk_bf16_f32 %0, %1, %2" : "=v"(r) : "v"(x), "v"(y));
    return r;
}
__device__ __forceinline__ float2 unpack_bf2(unsigned int v) {
    return make_float2(__uint_as_float(v << 16),
                       __uint_as_float(v & 0xffff0000u));
}
__device__ __forceinline__ unsigned short pack_bf1(float x) {
    unsigned int b = __float_as_uint(x);
    b += 0x7fffu + ((b >> 16) & 1u);
    return (unsigned short)(b >> 16);
}

__device__ __forceinline__ float head_reduce(float p) {
    p += __shfl_xor(p, 8, 16);
    p += __shfl_xor(p, 4, 16);
    p += __shfl_xor(p, 2, 16);
    p += __shfl_xor(p, 1, 16);
    return p;
}

// ---------------------------------------------------------------------------
// Weight prep: Bp holds 3 matrices in MFMA fragment order, bf16.
// ---------------------------------------------------------------------------
__global__ void wprep(const float* __restrict__ user_W, const float* __restrict__ user_b,
                      const float* __restrict__ c1_Wl, const float* __restrict__ c1_bl,
                      const float* __restrict__ c2_Wr, const float* __restrict__ c2_br,
                      const float* __restrict__ c2_Wl, unsigned short* __restrict__ Bp)
{
    const int t = blockIdx.x * 256 + threadIdx.x;   // 0..49151
    const int mat = t >> 14;
    const int k = (t >> 7) & 127;
    const int n = t & 127;
    float val = 0.f;
    if (mat == 2) {
        val = c2_Wl[k * 128 + n];
    } else {
        const float* W2 = mat ? c2_Wr : c1_Wl;
        if (k < 101) {
            for (int q = 0; q < 32; ++q) val = fmaf(user_W[k * 32 + q], W2[q * 128 + n], val);
        } else if (k == 101) {
            for (int q = 0; q < 32; ++q) val = fmaf(user_b[q], W2[q * 128 + n], val);
            val += (mat ? c2_br : c1_bl)[n];
        }
    }
    const int fi = (mat * 8 + (n >> 4)) * 4 + (k >> 5);
    const int lane_ = (n & 15) + ((k >> 3) & 3) * 16;
    Bp[(size_t)fi * 512 + lane_ * 8 + (k & 7)] = pack_bf1(val);
}

// ---------------------------------------------------------------------------
// W1 (classifier, 128x64) -> fragment order, 16 frags
// ---------------------------------------------------------------------------
__global__ void w1prep(const float* __restrict__ W1, unsigned short* __restrict__ Bp1)
{
    const int t = blockIdx.x * 256 + threadIdx.x;   // 0..8191
    const int k = t >> 6;
    const int n = t & 63;
    const float val = W1[k * 64 + n];
    const int fi = (n >> 4) * 4 + (k >> 5);
    const int lane_ = (n & 15) + ((k >> 3) & 3) * 16;
    Bp1[(size_t)fi * 512 + lane_ * 8 + (k & 7)] = pack_bf1(val);
}

// ---------------------------------------------------------------------------
// xr1 rank-1 weights: wv[j] = item_W@c1_Wr, bb[j] = item_b@c1_Wr + c1_br
// ---------------------------------------------------------------------------
__global__ void wvbb_prep(const float* __restrict__ item_W, const float* __restrict__ item_b,
                          const float* __restrict__ c1_Wr, const float* __restrict__ c1_br,
                          float* __restrict__ wvbb)
{
    const int j = threadIdx.x;
    if (j >= 128) return;
    float wv = 0.f, bb = 0.f;
    for (int q = 0; q < 32; ++q) {
        wv = fmaf(item_W[q], c1_Wr[q * 128 + j], wv);
        bb = fmaf(item_b[q], c1_Wr[q * 128 + j], bb);
    }
    wvbb[j] = wv;
    wvbb[128 + j] = bb + c1_br[j];
}

// ---------------------------------------------------------------------------
// HYBRID: blocks [0, nscat) run the atomic-free edge scatter (FIRST, so the
// latency-bound scatter fills the machine at t=0); blocks [nscat, ...) run
// the MFMA user projection (round-15 config). Data-independent roles.
// ---------------------------------------------------------------------------
__global__ __launch_bounds__(256)
void mfma_user_scatter(const float* __restrict__ cx, const unsigned short* __restrict__ Bp,
                       unsigned short* __restrict__ outL, unsigned short* __restrict__ outR,
                       int M, int nub,
                       const int* __restrict__ src, const int* __restrict__ dst,
                       const float* __restrict__ eattr,
                       const int* __restrict__ offU, const int* __restrict__ offI,
                       const int* __restrict__ rankU, const int* __restrict__ rankI,
                       int* __restrict__ sFund, uint4* __restrict__ sE1, int E, int nscat)
{
    __shared__ float xs[64 * 108];   // 27648 B

    if (blockIdx.x < nscat) {
        // ---- scatter role (dispatched first -> overlaps mfma from t=0) ----
        const int bid = blockIdx.x;
        for (int i = bid * 256 + threadIdx.x; i < E; i += nscat * 256) {
            const int s = src[i];
            const int d = dst[i];
            const float a0 = eattr[3 * (size_t)i];
            const float a1 = eattr[3 * (size_t)i + 1];
            const float a2 = eattr[3 * (size_t)i + 2];
            const int p1 = offI[d] + rankI[i];
            const int p2 = offU[s] + rankU[i];
            sE1[p1] = make_uint4((unsigned int)s, __float_as_uint(a0),
                                 __float_as_uint(a1), __float_as_uint(a2));
            sFund[p2] = d;
        }
        return;
    }

    // ---- MFMA projection role ----
    const int tid = threadIdx.x;
    const int lane = tid & 63;
    const int wid = tid >> 6;
    const int rowblk = (blockIdx.x - nscat) * 64;
    const int rows = min(64, M - rowblk);

    const float* srcp = cx + (size_t)rowblk * 101;
    const int total = rows * 101;
    for (int i = tid; i < total; i += 256) {
        const int r = i / 101;
        const int c = i - r * 101;
        xs[r * 108 + c] = srcp[i];
    }
    __syncthreads();

    const int rowbase = wid * 16;
    if (rowbase >= rows) return;
    const int row = lane & 15;
    const int chunk = lane >> 4;
    const float* rowp = xs + (rowbase + row) * 108;

    frag_u a[4];
    #pragma unroll
    for (int ks = 0; ks < 3; ++ks) {
        const int kb = ks * 32 + chunk * 8;
        const float4 p = *(const float4*)(rowp + kb);
        const float4 q = *(const float4*)(rowp + kb + 4);
        a[ks].u[0] = pack_bf2(p.x, p.y);
        a[ks].u[1] = pack_bf2(p.z, p.w);
        a[ks].u[2] = pack_bf2(q.x, q.y);
        a[ks].u[3] = pack_bf2(q.z, q.w);
    }
    {   // kstep 3: k 96..100 real, k=101 -> 1.0 (bias row), rest 0
        float v0 = 0.f, v1 = 0.f, v2 = 0.f, v3 = 0.f, v4 = 0.f, v5 = 0.f;
        if (chunk == 0) {
            const float4 p = *(const float4*)(rowp + 96);
            v0 = p.x; v1 = p.y; v2 = p.z; v3 = p.w;
            v4 = rowp[100];
            v5 = 1.0f;
        }
        a[3].u[0] = pack_bf2(v0, v1);
        a[3].u[1] = pack_bf2(v2, v3);
        a[3].u[2] = pack_bf2(v4, v5);
        a[3].u[3] = 0u;
    }

    unsigned short* xpo = (unsigned short*)(xs + (size_t)wid * 16 * 108);

    const bf16x8* bfr = (const bf16x8*)Bp;
    #pragma unroll
    for (int mat = 0; mat < 2; ++mat) {
        unsigned short* outp = mat ? outR : outL;
        #pragma unroll
        for (int nf = 0; nf < 8; ++nf) {
            f32x4 acc = {0.f, 0.f, 0.f, 0.f};
            const int fi = (mat * 8 + nf) * 4;
            acc = __builtin_amdgcn_mfma_f32_16x16x32_bf16(a[0].v, bfr[(fi + 0) * 64 + lane], acc, 0, 0, 0);
            acc = __builtin_amdgcn_mfma_f32_16x16x32_bf16(a[1].v, bfr[(fi + 1) * 64 + lane], acc, 0, 0, 0);
            acc = __builtin_amdgcn_mfma_f32_16x16x32_bf16(a[2].v, bfr[(fi + 2) * 64 + lane], acc, 0, 0, 0);
            acc = __builtin_amdgcn_mfma_f32_16x16x32_bf16(a[3].v, bfr[(fi + 3) * 64 + lane], acc, 0, 0, 0);
            const int col = nf * 16 + row;
            #pragma unroll
            for (int j = 0; j < 4; ++j)
                xpo[(chunk * 4 + j) * 140 + col] = pack_bf1(acc[j]);
        }
        #pragma unroll
        for (int i = 0; i < 4; ++i) {
            const int r = i * 4 + chunk;
            const bf16x8 v = *(const bf16x8*)&xpo[r * 140 + row * 8];
            *(bf16x8*)(outp + (size_t)(rowblk + rowbase + r) * 128 + row * 8) = v;
        }
    }
}

// ---------------------------------------------------------------------------
// MFMA: xl2 = item_h[NI,128] @ c2_Wl + c2_bl -> bf16
// ---------------------------------------------------------------------------
__global__ __launch_bounds__(256)
void mfma_xl2(const float* __restrict__ X, const unsigned short* __restrict__ Bp,
              const float* __restrict__ bias, unsigned short* __restrict__ outp, int M)
{
    const int lane = threadIdx.x & 63;
    const int wt = (blockIdx.x * blockDim.x + threadIdx.x) >> 6;
    const int rowbase = wt * 16;
    if (rowbase >= M) return;
    const int chunk = lane >> 4;
    const float* rowp = X + (size_t)(rowbase + (lane & 15)) * 128;

    frag_u a[4];
    #pragma unroll
    for (int ks = 0; ks < 4; ++ks) {
        const int kb = ks * 32 + chunk * 8;
        const float4 p = *(const float4*)(rowp + kb);
        const float4 q = *(const float4*)(rowp + kb + 4);
        a[ks].u[0] = pack_bf2(p.x, p.y);
        a[ks].u[1] = pack_bf2(p.z, p.w);
        a[ks].u[2] = pack_bf2(q.x, q.y);
        a[ks].u[3] = pack_bf2(q.z, q.w);
    }

    const bf16x8* bfr = (const bf16x8*)Bp;
    #pragma unroll
    for (int nf = 0; nf < 8; ++nf) {
        f32x4 acc = {0.f, 0.f, 0.f, 0.f};
        const int fi = (16 + nf) * 4;   // mat 2
        acc = __builtin_amdgcn_mfma_f32_16x16x32_bf16(a[0].v, bfr[(fi + 0) * 64 + lane], acc, 0, 0, 0);
        acc = __builtin_amdgcn_mfma_f32_16x16x32_bf16(a[1].v, bfr[(fi + 1) * 64 + lane], acc, 0, 0, 0);
        acc = __builtin_amdgcn_mfma_f32_16x16x32_bf16(a[2].v, bfr[(fi + 2) * 64 + lane], acc, 0, 0, 0);
        acc = __builtin_amdgcn_mfma_f32_16x16x32_bf16(a[3].v, bfr[(fi + 3) * 64 + lane], acc, 0, 0, 0);
        const int col = nf * 16 + (lane & 15);
        const float bv = bias[col];
        #pragma unroll
        for (int j = 0; j < 4; ++j)
            outp[(size_t)(rowbase + chunk * 4 + j) * 128 + col] = pack_bf1(acc[j] + bv);
    }
}

// ---------------------------------------------------------------------------
// CSR build: hist + rank capture (atomics paid ONCE here)
// ---------------------------------------------------------------------------
__global__ void hist_rank(const int* __restrict__ src, const int* __restrict__ dst,
                          int* __restrict__ cntU, int* __restrict__ cntI,
                          int* __restrict__ rankU, int* __restrict__ rankI, int E)
{
    for (int i = blockIdx.x * blockDim.x + threadIdx.x; i < E;
         i += gridDim.x * blockDim.x) {
        rankU[i] = atomicAdd(&cntU[src[i]], 1);
        rankI[i] = atomicAdd(&cntI[dst[i]], 1);
    }
}

__global__ void scan_blocks(const int* __restrict__ in, int* __restrict__ out,
                            int* __restrict__ blockSums, int n)
{
    __shared__ int lds[256];
    const int tid = threadIdx.x;
    const int base = blockIdx.x * 1024 + tid * 4;
    int v[4];
    #pragma unroll
    for (int j = 0; j < 4; ++j) { int idx = base + j; v[j] = (idx < n) ? in[idx] : 0; }
    int t = v[0] + v[1] + v[2] + v[3];
    lds[tid] = t;
    __syncthreads();
    for (int off = 1; off < 256; off <<= 1) {
        int x = (tid >= off) ? lds[tid - off] : 0;
        __syncthreads();
        lds[tid] += x;
        __syncthreads();
    }
    int excl = lds[tid] - t;
    if (tid == 255 && blockSums) blockSums[blockIdx.x] = lds[255];
    int run = excl;
    #pragma unroll
    for (int j = 0; j < 4; ++j) {
        int idx = base + j;
        if (idx < n) out[idx] = run;
        run += v[j];
    }
}

__global__ void scan_add(int* __restrict__ out, const int* __restrict__ bss, int n)
{
    const int add = bss[blockIdx.x];
    const int base = blockIdx.x * 1024 + threadIdx.x * 4;
    #pragma unroll
    for (int j = 0; j < 4; ++j) { int idx = base + j; if (idx < n) out[idx] += add; }
}

// ---------------------------------------------------------------------------
// conv1 fused: one wave per fund d; 8-deep gather pipeline.
// xr1 computed ON THE FLY from fund_x (rank-1): vr = fund_x[d]*wv + bb.
// ---------------------------------------------------------------------------
__device__ __forceinline__ void conv1_edge(uint4 e, unsigned int vbits, float2 vr,
                                           float2 av, float2 w0, float2 w1, float2 w2,
                                           float& acc0, float& acc1, float& s)
{
    const float2 vl = unpack_bf2(vbits);
    const float e0 = __uint_as_float(e.y);
    const float e1 = __uint_as_float(e.z);
    const float e2 = __uint_as_float(e.w);
    float h0 = vl.x + vr.x + e0 * w0.x + e1 * w1.x + e2 * w2.x;
    float h1 = vl.y + vr.y + e0 * w0.y + e1 * w1.y + e2 * w2.y;
    h0 = h0 > 0.f ? h0 : 0.2f * h0;
    h1 = h1 > 0.f ? h1 : 0.2f * h1;
    const float p = head_reduce(h0 * av.x + h1 * av.y);
    const float ex = __expf(p);
    acc0 = fmaf(ex, vl.x, acc0);
    acc1 = fmaf(ex, vl.y, acc1);
    s += ex;
}

__global__ void conv1_fused(const unsigned int* __restrict__ xl,
                            const float* __restrict__ fund_x,
                            const float* __restrict__ wvbb,
                            const int* __restrict__ offI, const int* __restrict__ cnt,
                            const uint4* __restrict__ sE,
                            const float* __restrict__ We, const float* __restrict__ att,
                            const float* __restrict__ bias,
                            float* __restrict__ outF, int ndst)
{
    const int tid = threadIdx.x;
    const int lane = tid & 63;
    const int wid = tid >> 6;
    const int d = blockIdx.x * 4 + wid;
    if (d >= ndst) return;

    const int ch = lane * 2;
    const float2 av = *(const float2*)(att + ch);
    const float2 w0 = *(const float2*)(We + ch);
    const float2 w1 = *(const float2*)(We + HC + ch);
    const float2 w2 = *(const float2*)(We + 2 * HC + ch);
    const float2 bv = *(const float2*)(bias + ch);

    // xr1 row on the fly
    const float fx = fund_x[d];
    const float2 wv = *(const float2*)(wvbb + ch);
    const float2 bb = *(const float2*)(wvbb + 128 + ch);
    const float2 vr = make_float2(fmaf(fx, wv.x, bb.x), fmaf(fx, wv.y, bb.y));

    const int start = offI[d];
    const int end = start + cnt[d];

    float acc0 = 0.f, acc1 = 0.f, s = 0.f;
    int pos = start;
    for (; pos + 8 <= end; pos += 8) {
        uint4 e[8];
        unsigned int v[8];
        #pragma unroll
        for (int j = 0; j < 8; ++j) e[j] = sE[pos + j];
        #pragma unroll
        for (int j = 0; j < 8; ++j) v[j] = xl[(size_t)e[j].x * 64 + lane];
        #pragma unroll
        for (int j = 0; j < 8; ++j)
            conv1_edge(e[j], v[j], vr, av, w0, w1, w2, acc0, acc1, s);
    }
    for (; pos + 4 <= end; pos += 4) {
        uint4 e[4];
        unsigned int v[4];
        #pragma unroll
        for (int j = 0; j < 4; ++j) e[j] = sE[pos + j];
        #pragma unroll
        for (int j = 0; j < 4; ++j) v[j] = xl[(size_t)e[j].x * 64 + lane];
        #pragma unroll
        for (int j = 0; j < 4; ++j)
            conv1_edge(e[j], v[j], vr, av, w0, w1, w2, acc0, acc1, s);
    }
    for (; pos < end; ++pos) {
        const uint4 e = sE[pos];
        const unsigned int v = xl[(size_t)e.x * 64 + lane];
        conv1_edge(e, v, vr, av, w0, w1, w2, acc0, acc1, s);
    }
    const float inv = 1.f / (s + 1e-16f);
    const float o0 = fmaxf(acc0 * inv + bv.x, 0.f);
    const float o1 = fmaxf(acc1 * inv + bv.y, 0.f);
    *(float2*)(outF + (size_t)d * HC + ch) = make_float2(o0, o1);
}

// ---------------------------------------------------------------------------
// conv2 + classifier fused: one wave per 16 users, FLATTENED edge stream.
// ---------------------------------------------------------------------------
__device__ __forceinline__ void conv2_edge(unsigned int vbits, float2 vr, float2 av,
                                           float& acc0, float& acc1, float& s)
{
    const float2 vl = unpack_bf2(vbits);
    float h0 = vl.x + vr.x;
    float h1 = vl.y + vr.y;
    h0 = h0 > 0.f ? h0 : 0.2f * h0;
    h1 = h1 > 0.f ? h1 : 0.2f * h1;
    const float p = head_reduce(h0 * av.x + h1 * av.y);
    const float ex = __expf(p);
    acc0 = fmaf(ex, vl.x, acc0);
    acc1 = fmaf(ex, vl.y, acc1);
    s += ex;
}

__global__ __launch_bounds__(256)
void conv2_cls(const unsigned int* __restrict__ xl2,
               const unsigned int* __restrict__ xr2,
               const int* __restrict__ offU, const int* __restrict__ cnt,
               const int* __restrict__ sFund,
               const float* __restrict__ att, const float* __restrict__ cbias,
               const unsigned short* __restrict__ Bp1,
               const float* __restrict__ b1, const float* __restrict__ W2,
               const float* __restrict__ b2,
               float* __restrict__ out, int nusr)
{
    __shared__ unsigned short xs[4][16][136];

    const int lane = threadIdx.x & 63;
    const int wid = threadIdx.x >> 6;
    const int wt = (blockIdx.x * blockDim.x + threadIdx.x) >> 6;
    const int u0 = wt * 16;
    if (u0 >= nusr) return;

    const int ch = lane * 2;
    const float2 av = *(const float2*)(att + ch);
    const float2 bv = *(const float2*)(cbias + ch);

    // lane-parallel offsets for this wave's 16 users (NU % 16 == 0)
    int so = 0, ctv = 0;
    if (lane < 16) {
        so = offU[u0 + lane];
        ctv = cnt[u0 + lane];
    }
    const int eo = so + ctv;   // bucket end per lane
    const int S = __builtin_amdgcn_readlane(so, 0);
    const int E = __builtin_amdgcn_readlane(eo, 15);

    int u = 0;
    int end_u = __builtin_amdgcn_readlane(eo, 0);
    unsigned int vrb_next = xr2[(size_t)(u0 + 1) * 64 + lane];
    float2 vr = unpack_bf2(xr2[(size_t)u0 * 64 + lane]);
    float acc0 = 0.f, acc1 = 0.f, s = 0.f;

    #define FINALIZE() {                                                        \
        const float inv = 1.f / (s + 1e-16f);                                   \
        *(unsigned int*)&xs[wid][u][ch] = pack_bf2(acc0 * inv + bv.x,           \
                                                   acc1 * inv + bv.y);          \
        acc0 = acc1 = s = 0.f;                                                  \
        ++u;                                                                    \
        if (u < 16) {                                                           \
            end_u = __builtin_amdgcn_readlane(eo, u);                           \
            vr = unpack_bf2(vrb_next);                                          \
            if (u + 1 < 16) vrb_next = xr2[(size_t)(u0 + u + 1) * 64 + lane];   \
        }                                                                       \
    }

    int pos = S;
    while (pos < E) {
        const int f0 = sFund[pos];
        const int f1 = (pos + 1 < E) ? sFund[pos + 1] : f0;
        const int f2 = (pos + 2 < E) ? sFund[pos + 2] : f0;
        const int f3 = (pos + 3 < E) ? sFund[pos + 3] : f0;
        const unsigned int v0 = xl2[(size_t)f0 * 64 + lane];
        const unsigned int v1 = xl2[(size_t)f1 * 64 + lane];
        const unsigned int v2 = xl2[(size_t)f2 * 64 + lane];
        const unsigned int v3 = xl2[(size_t)f3 * 64 + lane];

        while (pos == end_u) FINALIZE();
        conv2_edge(v0, vr, av, acc0, acc1, s);
        if (pos + 1 < E) {
            while (pos + 1 == end_u) FINALIZE();
            conv2_edge(v1, vr, av, acc0, acc1, s);
        }
        if (pos + 2 < E) {
            while (pos + 2 == end_u) FINALIZE();
            conv2_edge(v2, vr, av, acc0, acc1, s);
        }
        if (pos + 3 < E) {
            while (pos + 3 == end_u) FINALIZE();
            conv2_edge(v3, vr, av, acc0, acc1, s);
        }
        pos += 4;
    }
    while (u < 16) FINALIZE();
    #undef FINALIZE

    // --- phase 2: MLP via MFMA (A = 16 user rows, K=128) ---
    const int row = lane & 15;
    const int chunk = lane >> 4;
    bf16x8 a[4];
    #pragma unroll
    for (int ks = 0; ks < 4; ++ks)
        a[ks] = *(const bf16x8*)&xs[wid][row][ks * 32 + chunk * 8];

    const bf16x8* bfr = (const bf16x8*)Bp1;
    float racc[4] = {0.f, 0.f, 0.f, 0.f};
    #pragma unroll
    for (int g = 0; g < 4; ++g) {
        f32x4 acc = {0.f, 0.f, 0.f, 0.f};
        const int fi = g * 4;
        acc = __builtin_amdgcn_mfma_f32_16x16x32_bf16(a[0], bfr[(fi + 0) * 64 + lane], acc, 0, 0, 0);
        acc = __builtin_amdgcn_mfma_f32_16x16x32_bf16(a[1], bfr[(fi + 1) * 64 + lane], acc, 0, 0, 0);
        acc = __builtin_amdgcn_mfma_f32_16x16x32_bf16(a[2], bfr[(fi + 2) * 64 + lane], acc, 0, 0, 0);
        acc = __builtin_amdgcn_mfma_f32_16x16x32_bf16(a[3], bfr[(fi + 3) * 64 + lane], acc, 0, 0, 0);
        const int col = g * 16 + row;
        const float b1v = b1[col];
        const float w2v = W2[col];
        #pragma unroll
        for (int j = 0; j < 4; ++j)
            racc[j] = fmaf(fmaxf(acc[j] + b1v, 0.f), w2v, racc[j]);
    }
    #pragma unroll
    for (int j = 0; j < 4; ++j) {
        racc[j] += __shfl_xor(racc[j], 1, 16);
        racc[j] += __shfl_xor(racc[j], 2, 16);
        racc[j] += __shfl_xor(racc[j], 4, 16);
        racc[j] += __shfl_xor(racc[j], 8, 16);
    }
    if (row == 0) {
        const float b2v = b2[0];
        #pragma unroll
        for (int j = 0; j < 4; ++j) {
            const int r = u0 + chunk * 4 + j;
            if (r < nusr) out[r] = 1.f / (1.f + expf(-(racc[j] + b2v)));
        }
    }
}

// ---------------------------------------------------------------------------
extern "C" void kernel_launch(void* const* d_in, const int* in_sizes, int n_in,
                              void* d_out, int out_size, void* d_ws, size_t ws_size,
                              hipStream_t stream)
{
    const float* customer_x = (const float*)d_in[0];
    const float* fund_x     = (const float*)d_in[1];
    const float* edge_attr  = (const float*)d_in[2];
    const int*   edge_src   = (const int*)d_in[3];
    const int*   edge_dst   = (const int*)d_in[4];
    const float* user_W = (const float*)d_in[5];
    const float* user_b = (const float*)d_in[6];
    const float* item_W = (const float*)d_in[7];
    const float* item_b = (const float*)d_in[8];
    const float* c1_Wl  = (const float*)d_in[9];
    const float* c1_bl  = (const float*)d_in[10];
    const float* c1_Wr  = (const float*)d_in[11];
    const float* c1_br  = (const float*)d_in[12];
    const float* c1_We  = (const float*)d_in[13];
    const float* c1_att = (const float*)d_in[14];
    const float* c1_bias= (const float*)d_in[15];
    const float* c2_Wl  = (const float*)d_in[16];
    const float* c2_bl  = (const float*)d_in[17];
    const float* c2_Wr  = (const float*)d_in[18];
    const float* c2_br  = (const float*)d_in[19];
    const float* c2_att = (const float*)d_in[20];
    const float* c2_bias= (const float*)d_in[21];
    const float* cls_W1 = (const float*)d_in[22];
    const float* cls_b1 = (const float*)d_in[23];
    const float* cls_W2 = (const float*)d_in[24];
    const float* cls_b2 = (const float*)d_in[25];
    float* out = (float*)d_out;

    float* ws = (float*)d_ws;
    size_t off = 0;
    unsigned short* B1 = (unsigned short*)(ws + off); off += (size_t)NU * 64; // xl1 bf16
    unsigned short* B2 = (unsigned short*)(ws + off); off += (size_t)NU * 64; // xr2 bf16
    float* F = ws + off; off += (size_t)NI * HC;                              // item_h fp32
    unsigned short* G = (unsigned short*)(ws + off); off += (size_t)NI * 64;  // xl2 bf16
    int* cnt1  = (int*)(ws + off); off += NI;
    int* off1  = (int*)(ws + off); off += NI;
    int* cnt2  = (int*)(ws + off); off += NU;
    int* off2  = (int*)(ws + off); off += NU;
    int* bs    = (int*)(ws + off); off += 1024;
    int* bss   = (int*)(ws + off); off += 1024;
    uint4* sE1 = (uint4*)(ws + off); off += (size_t)NE * 4;
    int* sFund = (int*)(ws + off); off += NE;
    int* rankU = (int*)(ws + off); off += NE;
    int* rankI = (int*)(ws + off); off += NE;
    unsigned short* Bp = (unsigned short*)(ws + off); off += 12288 + 256;     // 96KB frags
    unsigned short* Bp1 = (unsigned short*)(ws + off); off += 4096 + 256;     // 16KB W1 frags
    float* wvbb = ws + off; off += 256;

    hipMemsetAsync(cnt1, 0, NI * sizeof(int), stream);
    hipMemsetAsync(cnt2, 0, NU * sizeof(int), stream);

    // CSR build: rank-capturing histogram -> scan
    hist_rank<<<1024, 256, 0, stream>>>(edge_src, edge_dst, cnt2, cnt1,
                                        rankU, rankI, NE);
    const int nb1 = (NI + 1023) / 1024;
    const int nb2 = (NU + 1023) / 1024;
    scan_blocks<<<nb1, 256, 0, stream>>>(cnt1, off1, bs, NI);
    scan_blocks<<<1,   256, 0, stream>>>(bs, bss, nullptr, nb1);
    scan_add<<<nb1, 256, 0, stream>>>(off1, bss, NI);
    scan_blocks<<<nb2, 256, 0, stream>>>(cnt2, off2, bs, NU);
    scan_blocks<<<1,   256, 0, stream>>>(bs, bss, nullptr, nb2);
    scan_add<<<nb2, 256, 0, stream>>>(off2, bss, NU);

    // weight prep
    wprep<<<192, 256, 0, stream>>>(user_W, user_b, c1_Wl, c1_bl,
                                   c2_Wr, c2_br, c2_Wl, Bp);
    w1prep<<<32, 256, 0, stream>>>(cls_W1, Bp1);
    wvbb_prep<<<1, 128, 0, stream>>>(item_W, item_b, c1_Wr, c1_br, wvbb);

    // HYBRID: edge scatter (blocks 0..nscat, dispatched FIRST) + MFMA user
    // projection (remaining blocks)
    const int nub = (NU + 63) / 64;   // 7813
    const int nscat = 2048;
    mfma_user_scatter<<<nscat + nub, 256, 0, stream>>>(
        customer_x, Bp, B1, B2, NU, nub,
        edge_src, edge_dst, edge_attr, off2, off1, rankU, rankI,
        sFund, sE1, NE, nscat);

    // conv1: customer -> fund (+bias+relu), xr1 on-the-fly, fp32 out F
    conv1_fused<<<NI / 4, 256, 0, stream>>>((const unsigned int*)B1, fund_x, wvbb,
                                            off1, cnt1, sE1,
                                            c1_We, c1_att, c1_bias, F, NI);

    // xl2 = item_h @ c2_Wl + c2_bl (bf16)
    mfma_xl2<<<(NI / 16 + 3) / 4, 256, 0, stream>>>(F, Bp, c2_bl, G, NI);

    // conv2 + classifier fused: one wave per 16 users
    const int waves2 = (NU + 15) / 16;             // 31250
    conv2_cls<<<(waves2 + 3) / 4, 256, 0, stream>>>(
        (const unsigned int*)G, (const unsigned int*)B2, off2, cnt2, sFund,
        c2_att, c2_bias, Bp1, cls_b1, cls_W2, cls_b2, out, NU);
}

// Round 20
// 528.769 us; speedup vs baseline: 1.0213x; 1.0043x over previous
//
#include <hip/hip_runtime.h>
#include <cstdint>
#include <cstddef>

#define NU 500000
#define NI 50000
#define NE 1000000
#define HC 128   // H*C
#define NH 4

typedef __attribute__((ext_vector_type(8))) short bf16x8;
typedef __attribute__((ext_vector_type(4))) float f32x4;

union frag_u { bf16x8 v; unsigned int u[4]; };

// bf16 pack/unpack (RNE)
__device__ __forceinline__ unsigned int pack_bf2(float x, float y) {
    unsigned int r;
    asm("v_cvt_pk_bf16_f32 %0, %1, %2" : "=v"(r) : "v"(x), "v"(y));
    return r;
}
__device__ __forceinline__ float2 unpack_bf2(unsigned int v) {
    return make_float2(__uint_as_float(v << 16),
                       __uint_as_float(v & 0xffff0000u));
}
__device__ __forceinline__ unsigned short pack_bf1(float x) {
    unsigned int b = __float_as_uint(x);
    b += 0x7fffu + ((b >> 16) & 1u);
    return (unsigned short)(b >> 16);
}

__device__ __forceinline__ float head_reduce(float p) {
    p += __shfl_xor(p, 8, 16);
    p += __shfl_xor(p, 4, 16);
    p += __shfl_xor(p, 2, 16);
    p += __shfl_xor(p, 1, 16);
    return p;
}

// ---------------------------------------------------------------------------
// Weight prep: Bp holds 3 matrices in MFMA fragment order, bf16.
// ---------------------------------------------------------------------------
__global__ void wprep(const float* __restrict__ user_W, const float* __restrict__ user_b,
                      const float* __restrict__ c1_Wl, const float* __restrict__ c1_bl,
                      const float* __restrict__ c2_Wr, const float* __restrict__ c2_br,
                      const float* __restrict__ c2_Wl, unsigned short* __restrict__ Bp)
{
    const int t = blockIdx.x * 256 + threadIdx.x;   // 0..49151
    const int mat = t >> 14;
    const int k = (t >> 7) & 127;
    const int n = t & 127;
    float val = 0.f;
    if (mat == 2) {
        val = c2_Wl[k * 128 + n];
    } else {
        const float* W2 = mat ? c2_Wr : c1_Wl;
        if (k < 101) {
            for (int q = 0; q < 32; ++q) val = fmaf(user_W[k * 32 + q], W2[q * 128 + n], val);
        } else if (k == 101) {
            for (int q = 0; q < 32; ++q) val = fmaf(user_b[q], W2[q * 128 + n], val);
            val += (mat ? c2_br : c1_bl)[n];
        }
    }
    const int fi = (mat * 8 + (n >> 4)) * 4 + (k >> 5);
    const int lane_ = (n & 15) + ((k >> 3) & 3) * 16;
    Bp[(size_t)fi * 512 + lane_ * 8 + (k & 7)] = pack_bf1(val);
}

// ---------------------------------------------------------------------------
// W1 (classifier, 128x64) -> fragment order, 16 frags
// ---------------------------------------------------------------------------
__global__ void w1prep(const float* __restrict__ W1, unsigned short* __restrict__ Bp1)
{
    const int t = blockIdx.x * 256 + threadIdx.x;   // 0..8191
    const int k = t >> 6;
    const int n = t & 63;
    const float val = W1[k * 64 + n];
    const int fi = (n >> 4) * 4 + (k >> 5);
    const int lane_ = (n & 15) + ((k >> 3) & 3) * 16;
    Bp1[(size_t)fi * 512 + lane_ * 8 + (k & 7)] = pack_bf1(val);
}

// ---------------------------------------------------------------------------
// xr1 rank-1 weights: wv[j] = item_W@c1_Wr, bb[j] = item_b@c1_Wr + c1_br
// ---------------------------------------------------------------------------
__global__ void wvbb_prep(const float* __restrict__ item_W, const float* __restrict__ item_b,
                          const float* __restrict__ c1_Wr, const float* __restrict__ c1_br,
                          float* __restrict__ wvbb)
{
    const int j = threadIdx.x;
    if (j >= 128) return;
    float wv = 0.f, bb = 0.f;
    for (int q = 0; q < 32; ++q) {
        wv = fmaf(item_W[q], c1_Wr[q * 128 + j], wv);
        bb = fmaf(item_b[q], c1_Wr[q * 128 + j], bb);
    }
    wvbb[j] = wv;
    wvbb[128 + j] = bb + c1_br[j];
}

// ---------------------------------------------------------------------------
// MFMA user-projection role (round-15 config), shared by both hybrid kernels.
// ---------------------------------------------------------------------------
__device__ __forceinline__
void mfma_role(float* xs, const float* __restrict__ cx,
               const unsigned short* __restrict__ Bp,
               unsigned short* __restrict__ outL, unsigned short* __restrict__ outR,
               int M, int rowblk, int tid)
{
    const int lane = tid & 63;
    const int wid = tid >> 6;
    const int rows = min(64, M - rowblk);

    const float* srcp = cx + (size_t)rowblk * 101;
    const int total = rows * 101;
    for (int i = tid; i < total; i += 256) {
        const int r = i / 101;
        const int c = i - r * 101;
        xs[r * 108 + c] = srcp[i];
    }
    __syncthreads();

    const int rowbase = wid * 16;
    if (rowbase >= rows) return;
    const int row = lane & 15;
    const int chunk = lane >> 4;
    const float* rowp = xs + (rowbase + row) * 108;

    frag_u a[4];
    #pragma unroll
    for (int ks = 0; ks < 3; ++ks) {
        const int kb = ks * 32 + chunk * 8;
        const float4 p = *(const float4*)(rowp + kb);
        const float4 q = *(const float4*)(rowp + kb + 4);
        a[ks].u[0] = pack_bf2(p.x, p.y);
        a[ks].u[1] = pack_bf2(p.z, p.w);
        a[ks].u[2] = pack_bf2(q.x, q.y);
        a[ks].u[3] = pack_bf2(q.z, q.w);
    }
    {   // kstep 3: k 96..100 real, k=101 -> 1.0 (bias row), rest 0
        float v0 = 0.f, v1 = 0.f, v2 = 0.f, v3 = 0.f, v4 = 0.f, v5 = 0.f;
        if (chunk == 0) {
            const float4 p = *(const float4*)(rowp + 96);
            v0 = p.x; v1 = p.y; v2 = p.z; v3 = p.w;
            v4 = rowp[100];
            v5 = 1.0f;
        }
        a[3].u[0] = pack_bf2(v0, v1);
        a[3].u[1] = pack_bf2(v2, v3);
        a[3].u[2] = pack_bf2(v4, v5);
        a[3].u[3] = 0u;
    }

    unsigned short* xpo = (unsigned short*)(xs + (size_t)wid * 16 * 108);

    const bf16x8* bfr = (const bf16x8*)Bp;
    #pragma unroll
    for (int mat = 0; mat < 2; ++mat) {
        unsigned short* outp = mat ? outR : outL;
        #pragma unroll
        for (int nf = 0; nf < 8; ++nf) {
            f32x4 acc = {0.f, 0.f, 0.f, 0.f};
            const int fi = (mat * 8 + nf) * 4;
            acc = __builtin_amdgcn_mfma_f32_16x16x32_bf16(a[0].v, bfr[(fi + 0) * 64 + lane], acc, 0, 0, 0);
            acc = __builtin_amdgcn_mfma_f32_16x16x32_bf16(a[1].v, bfr[(fi + 1) * 64 + lane], acc, 0, 0, 0);
            acc = __builtin_amdgcn_mfma_f32_16x16x32_bf16(a[2].v, bfr[(fi + 2) * 64 + lane], acc, 0, 0, 0);
            acc = __builtin_amdgcn_mfma_f32_16x16x32_bf16(a[3].v, bfr[(fi + 3) * 64 + lane], acc, 0, 0, 0);
            const int col = nf * 16 + row;
            #pragma unroll
            for (int j = 0; j < 4; ++j)
                xpo[(chunk * 4 + j) * 140 + col] = pack_bf1(acc[j]);
        }
        #pragma unroll
        for (int i = 0; i < 4; ++i) {
            const int r = i * 4 + chunk;
            const bf16x8 v = *(const bf16x8*)&xpo[r * 140 + row * 8];
            *(bf16x8*)(outp + (size_t)(rowblk + rowbase + r) * 128 + row * 8) = v;
        }
    }
}

// ---------------------------------------------------------------------------
// HYBRID 1: blocks [0,nhist) = rank-capturing histogram; rest = MFMA rows
// [0, nubA*64). hist is atomic-latency-bound; mfma fills idle slots.
// ---------------------------------------------------------------------------
__global__ __launch_bounds__(256)
void hist_mfma(const int* __restrict__ src, const int* __restrict__ dst,
               int* __restrict__ cntU, int* __restrict__ cntI,
               int* __restrict__ rankU, int* __restrict__ rankI, int E, int nhist,
               const float* __restrict__ cx, const unsigned short* __restrict__ Bp,
               unsigned short* __restrict__ outL, unsigned short* __restrict__ outR, int M)
{
    __shared__ float xs[64 * 108];

    if (blockIdx.x < nhist) {
        for (int i = blockIdx.x * 256 + threadIdx.x; i < E; i += nhist * 256) {
            rankU[i] = atomicAdd(&cntU[src[i]], 1);
            rankI[i] = atomicAdd(&cntI[dst[i]], 1);
        }
        return;
    }
    mfma_role(xs, cx, Bp, outL, outR, M, (blockIdx.x - nhist) * 64, threadIdx.x);
}

// ---------------------------------------------------------------------------
// HYBRID 2: blocks [0,nscat) = atomic-free scatter; rest = MFMA rows
// [rowoff, M).
// ---------------------------------------------------------------------------
__global__ __launch_bounds__(256)
void scat_mfma(const int* __restrict__ src, const int* __restrict__ dst,
               const float* __restrict__ eattr,
               const int* __restrict__ offU, const int* __restrict__ offI,
               const int* __restrict__ rankU, const int* __restrict__ rankI,
               int* __restrict__ sFund, uint4* __restrict__ sE1, int E, int nscat,
               const float* __restrict__ cx, const unsigned short* __restrict__ Bp,
               unsigned short* __restrict__ outL, unsigned short* __restrict__ outR,
               int M, int rowoff)
{
    __shared__ float xs[64 * 108];

    if (blockIdx.x < nscat) {
        for (int i = blockIdx.x * 256 + threadIdx.x; i < E; i += nscat * 256) {
            const int s = src[i];
            const int d = dst[i];
            const float a0 = eattr[3 * (size_t)i];
            const float a1 = eattr[3 * (size_t)i + 1];
            const float a2 = eattr[3 * (size_t)i + 2];
            const int p1 = offI[d] + rankI[i];
            const int p2 = offU[s] + rankU[i];
            sE1[p1] = make_uint4((unsigned int)s, __float_as_uint(a0),
                                 __float_as_uint(a1), __float_as_uint(a2));
            sFund[p2] = d;
        }
        return;
    }
    mfma_role(xs, cx, Bp, outL, outR, M,
              rowoff + (blockIdx.x - nscat) * 64, threadIdx.x);
}

// ---------------------------------------------------------------------------
// MFMA: xl2 = item_h[NI,128] @ c2_Wl + c2_bl -> bf16
// ---------------------------------------------------------------------------
__global__ __launch_bounds__(256)
void mfma_xl2(const float* __restrict__ X, const unsigned short* __restrict__ Bp,
              const float* __restrict__ bias, unsigned short* __restrict__ outp, int M)
{
    const int lane = threadIdx.x & 63;
    const int wt = (blockIdx.x * blockDim.x + threadIdx.x) >> 6;
    const int rowbase = wt * 16;
    if (rowbase >= M) return;
    const int chunk = lane >> 4;
    const float* rowp = X + (size_t)(rowbase + (lane & 15)) * 128;

    frag_u a[4];
    #pragma unroll
    for (int ks = 0; ks < 4; ++ks) {
        const int kb = ks * 32 + chunk * 8;
        const float4 p = *(const float4*)(rowp + kb);
        const float4 q = *(const float4*)(rowp + kb + 4);
        a[ks].u[0] = pack_bf2(p.x, p.y);
        a[ks].u[1] = pack_bf2(p.z, p.w);
        a[ks].u[2] = pack_bf2(q.x, q.y);
        a[ks].u[3] = pack_bf2(q.z, q.w);
    }

    const bf16x8* bfr = (const bf16x8*)Bp;
    #pragma unroll
    for (int nf = 0; nf < 8; ++nf) {
        f32x4 acc = {0.f, 0.f, 0.f, 0.f};
        const int fi = (16 + nf) * 4;   // mat 2
        acc = __builtin_amdgcn_mfma_f32_16x16x32_bf16(a[0].v, bfr[(fi + 0) * 64 + lane], acc, 0, 0, 0);
        acc = __builtin_amdgcn_mfma_f32_16x16x32_bf16(a[1].v, bfr[(fi + 1) * 64 + lane], acc, 0, 0, 0);
        acc = __builtin_amdgcn_mfma_f32_16x16x32_bf16(a[2].v, bfr[(fi + 2) * 64 + lane], acc, 0, 0, 0);
        acc = __builtin_amdgcn_mfma_f32_16x16x32_bf16(a[3].v, bfr[(fi + 3) * 64 + lane], acc, 0, 0, 0);
        const int col = nf * 16 + (lane & 15);
        const float bv = bias[col];
        #pragma unroll
        for (int j = 0; j < 4; ++j)
            outp[(size_t)(rowbase + chunk * 4 + j) * 128 + col] = pack_bf1(acc[j] + bv);
    }
}

__global__ void scan_blocks(const int* __restrict__ in, int* __restrict__ out,
                            int* __restrict__ blockSums, int n)
{
    __shared__ int lds[256];
    const int tid = threadIdx.x;
    const int base = blockIdx.x * 1024 + tid * 4;
    int v[4];
    #pragma unroll
    for (int j = 0; j < 4; ++j) { int idx = base + j; v[j] = (idx < n) ? in[idx] : 0; }
    int t = v[0] + v[1] + v[2] + v[3];
    lds[tid] = t;
    __syncthreads();
    for (int off = 1; off < 256; off <<= 1) {
        int x = (tid >= off) ? lds[tid - off] : 0;
        __syncthreads();
        lds[tid] += x;
        __syncthreads();
    }
    int excl = lds[tid] - t;
    if (tid == 255 && blockSums) blockSums[blockIdx.x] = lds[255];
    int run = excl;
    #pragma unroll
    for (int j = 0; j < 4; ++j) {
        int idx = base + j;
        if (idx < n) out[idx] = run;
        run += v[j];
    }
}

__global__ void scan_add(int* __restrict__ out, const int* __restrict__ bss, int n)
{
    const int add = bss[blockIdx.x];
    const int base = blockIdx.x * 1024 + threadIdx.x * 4;
    #pragma unroll
    for (int j = 0; j < 4; ++j) { int idx = base + j; if (idx < n) out[idx] += add; }
}

// ---------------------------------------------------------------------------
// conv1 fused: one wave per fund d; 8-deep gather pipeline.
// xr1 computed ON THE FLY from fund_x (rank-1): vr = fund_x[d]*wv + bb.
// ---------------------------------------------------------------------------
__device__ __forceinline__ void conv1_edge(uint4 e, unsigned int vbits, float2 vr,
                                           float2 av, float2 w0, float2 w1, float2 w2,
                                           float& acc0, float& acc1, float& s)
{
    const float2 vl = unpack_bf2(vbits);
    const float e0 = __uint_as_float(e.y);
    const float e1 = __uint_as_float(e.z);
    const float e2 = __uint_as_float(e.w);
    float h0 = vl.x + vr.x + e0 * w0.x + e1 * w1.x + e2 * w2.x;
    float h1 = vl.y + vr.y + e0 * w0.y + e1 * w1.y + e2 * w2.y;
    h0 = h0 > 0.f ? h0 : 0.2f * h0;
    h1 = h1 > 0.f ? h1 : 0.2f * h1;
    const float p = head_reduce(h0 * av.x + h1 * av.y);
    const float ex = __expf(p);
    acc0 = fmaf(ex, vl.x, acc0);
    acc1 = fmaf(ex, vl.y, acc1);
    s += ex;
}

__global__ void conv1_fused(const unsigned int* __restrict__ xl,
                            const float* __restrict__ fund_x,
                            const float* __restrict__ wvbb,
                            const int* __restrict__ offI, const int* __restrict__ cnt,
                            const uint4* __restrict__ sE,
                            const float* __restrict__ We, const float* __restrict__ att,
                            const float* __restrict__ bias,
                            float* __restrict__ outF, int ndst)
{
    const int tid = threadIdx.x;
    const int lane = tid & 63;
    const int wid = tid >> 6;
    const int d = blockIdx.x * 4 + wid;
    if (d >= ndst) return;

    const int ch = lane * 2;
    const float2 av = *(const float2*)(att + ch);
    const float2 w0 = *(const float2*)(We + ch);
    const float2 w1 = *(const float2*)(We + HC + ch);
    const float2 w2 = *(const float2*)(We + 2 * HC + ch);
    const float2 bv = *(const float2*)(bias + ch);

    // xr1 row on the fly
    const float fx = fund_x[d];
    const float2 wv = *(const float2*)(wvbb + ch);
    const float2 bb = *(const float2*)(wvbb + 128 + ch);
    const float2 vr = make_float2(fmaf(fx, wv.x, bb.x), fmaf(fx, wv.y, bb.y));

    const int start = offI[d];
    const int end = start + cnt[d];

    float acc0 = 0.f, acc1 = 0.f, s = 0.f;
    int pos = start;
    for (; pos + 8 <= end; pos += 8) {
        uint4 e[8];
        unsigned int v[8];
        #pragma unroll
        for (int j = 0; j < 8; ++j) e[j] = sE[pos + j];
        #pragma unroll
        for (int j = 0; j < 8; ++j) v[j] = xl[(size_t)e[j].x * 64 + lane];
        #pragma unroll
        for (int j = 0; j < 8; ++j)
            conv1_edge(e[j], v[j], vr, av, w0, w1, w2, acc0, acc1, s);
    }
    for (; pos + 4 <= end; pos += 4) {
        uint4 e[4];
        unsigned int v[4];
        #pragma unroll
        for (int j = 0; j < 4; ++j) e[j] = sE[pos + j];
        #pragma unroll
        for (int j = 0; j < 4; ++j) v[j] = xl[(size_t)e[j].x * 64 + lane];
        #pragma unroll
        for (int j = 0; j < 4; ++j)
            conv1_edge(e[j], v[j], vr, av, w0, w1, w2, acc0, acc1, s);
    }
    for (; pos < end; ++pos) {
        const uint4 e = sE[pos];
        const unsigned int v = xl[(size_t)e.x * 64 + lane];
        conv1_edge(e, v, vr, av, w0, w1, w2, acc0, acc1, s);
    }
    const float inv = 1.f / (s + 1e-16f);
    const float o0 = fmaxf(acc0 * inv + bv.x, 0.f);
    const float o1 = fmaxf(acc1 * inv + bv.y, 0.f);
    *(float2*)(outF + (size_t)d * HC + ch) = make_float2(o0, o1);
}

// ---------------------------------------------------------------------------
// conv2 + classifier fused: one wave per 16 users, FLATTENED edge stream.
// ---------------------------------------------------------------------------
__device__ __forceinline__ void conv2_edge(unsigned int vbits, float2 vr, float2 av,
                                           float& acc0, float& acc1, float& s)
{
    const float2 vl = unpack_bf2(vbits);
    float h0 = vl.x + vr.x;
    float h1 = vl.y + vr.y;
    h0 = h0 > 0.f ? h0 : 0.2f * h0;
    h1 = h1 > 0.f ? h1 : 0.2f * h1;
    const float p = head_reduce(h0 * av.x + h1 * av.y);
    const float ex = __expf(p);
    acc0 = fmaf(ex, vl.x, acc0);
    acc1 = fmaf(ex, vl.y, acc1);
    s += ex;
}

__global__ __launch_bounds__(256)
void conv2_cls(const unsigned int* __restrict__ xl2,
               const unsigned int* __restrict__ xr2,
               const int* __restrict__ offU, const int* __restrict__ cnt,
               const int* __restrict__ sFund,
               const float* __restrict__ att, const float* __restrict__ cbias,
               const unsigned short* __restrict__ Bp1,
               const float* __restrict__ b1, const float* __restrict__ W2,
               const float* __restrict__ b2,
               float* __restrict__ out, int nusr)
{
    __shared__ unsigned short xs[4][16][136];

    const int lane = threadIdx.x & 63;
    const int wid = threadIdx.x >> 6;
    const int wt = (blockIdx.x * blockDim.x + threadIdx.x) >> 6;
    const int u0 = wt * 16;
    if (u0 >= nusr) return;

    const int ch = lane * 2;
    const float2 av = *(const float2*)(att + ch);
    const float2 bv = *(const float2*)(cbias + ch);

    // lane-parallel offsets for this wave's 16 users (NU % 16 == 0)
    int so = 0, ctv = 0;
    if (lane < 16) {
        so = offU[u0 + lane];
        ctv = cnt[u0 + lane];
    }
    const int eo = so + ctv;   // bucket end per lane
    const int S = __builtin_amdgcn_readlane(so, 0);
    const int E = __builtin_amdgcn_readlane(eo, 15);

    int u = 0;
    int end_u = __builtin_amdgcn_readlane(eo, 0);
    unsigned int vrb_next = xr2[(size_t)(u0 + 1) * 64 + lane];
    float2 vr = unpack_bf2(xr2[(size_t)u0 * 64 + lane]);
    float acc0 = 0.f, acc1 = 0.f, s = 0.f;

    #define FINALIZE() {                                                        \
        const float inv = 1.f / (s + 1e-16f);                                   \
        *(unsigned int*)&xs[wid][u][ch] = pack_bf2(acc0 * inv + bv.x,           \
                                                   acc1 * inv + bv.y);          \
        acc0 = acc1 = s = 0.f;                                                  \
        ++u;                                                                    \
        if (u < 16) {                                                           \
            end_u = __builtin_amdgcn_readlane(eo, u);                           \
            vr = unpack_bf2(vrb_next);                                          \
            if (u + 1 < 16) vrb_next = xr2[(size_t)(u0 + u + 1) * 64 + lane];   \
        }                                                                       \
    }

    int pos = S;
    while (pos < E) {
        const int f0 = sFund[pos];
        const int f1 = (pos + 1 < E) ? sFund[pos + 1] : f0;
        const int f2 = (pos + 2 < E) ? sFund[pos + 2] : f0;
        const int f3 = (pos + 3 < E) ? sFund[pos + 3] : f0;
        const unsigned int v0 = xl2[(size_t)f0 * 64 + lane];
        const unsigned int v1 = xl2[(size_t)f1 * 64 + lane];
        const unsigned int v2 = xl2[(size_t)f2 * 64 + lane];
        const unsigned int v3 = xl2[(size_t)f3 * 64 + lane];

        while (pos == end_u) FINALIZE();
        conv2_edge(v0, vr, av, acc0, acc1, s);
        if (pos + 1 < E) {
            while (pos + 1 == end_u) FINALIZE();
            conv2_edge(v1, vr, av, acc0, acc1, s);
        }
        if (pos + 2 < E) {
            while (pos + 2 == end_u) FINALIZE();
            conv2_edge(v2, vr, av, acc0, acc1, s);
        }
        if (pos + 3 < E) {
            while (pos + 3 == end_u) FINALIZE();
            conv2_edge(v3, vr, av, acc0, acc1, s);
        }
        pos += 4;
    }
    while (u < 16) FINALIZE();
    #undef FINALIZE

    // --- phase 2: MLP via MFMA (A = 16 user rows, K=128) ---
    const int row = lane & 15;
    const int chunk = lane >> 4;
    bf16x8 a[4];
    #pragma unroll
    for (int ks = 0; ks < 4; ++ks)
        a[ks] = *(const bf16x8*)&xs[wid][row][ks * 32 + chunk * 8];

    const bf16x8* bfr = (const bf16x8*)Bp1;
    float racc[4] = {0.f, 0.f, 0.f, 0.f};
    #pragma unroll
    for (int g = 0; g < 4; ++g) {
        f32x4 acc = {0.f, 0.f, 0.f, 0.f};
        const int fi = g * 4;
        acc = __builtin_amdgcn_mfma_f32_16x16x32_bf16(a[0], bfr[(fi + 0) * 64 + lane], acc, 0, 0, 0);
        acc = __builtin_amdgcn_mfma_f32_16x16x32_bf16(a[1], bfr[(fi + 1) * 64 + lane], acc, 0, 0, 0);
        acc = __builtin_amdgcn_mfma_f32_16x16x32_bf16(a[2], bfr[(fi + 2) * 64 + lane], acc, 0, 0, 0);
        acc = __builtin_amdgcn_mfma_f32_16x16x32_bf16(a[3], bfr[(fi + 3) * 64 + lane], acc, 0, 0, 0);
        const int col = g * 16 + row;
        const float b1v = b1[col];
        const float w2v = W2[col];
        #pragma unroll
        for (int j = 0; j < 4; ++j)
            racc[j] = fmaf(fmaxf(acc[j] + b1v, 0.f), w2v, racc[j]);
    }
    #pragma unroll
    for (int j = 0; j < 4; ++j) {
        racc[j] += __shfl_xor(racc[j], 1, 16);
        racc[j] += __shfl_xor(racc[j], 2, 16);
        racc[j] += __shfl_xor(racc[j], 4, 16);
        racc[j] += __shfl_xor(racc[j], 8, 16);
    }
    if (row == 0) {
        const float b2v = b2[0];
        #pragma unroll
        for (int j = 0; j < 4; ++j) {
            const int r = u0 + chunk * 4 + j;
            if (r < nusr) out[r] = 1.f / (1.f + expf(-(racc[j] + b2v)));
        }
    }
}

// ---------------------------------------------------------------------------
extern "C" void kernel_launch(void* const* d_in, const int* in_sizes, int n_in,
                              void* d_out, int out_size, void* d_ws, size_t ws_size,
                              hipStream_t stream)
{
    const float* customer_x = (const float*)d_in[0];
    const float* fund_x     = (const float*)d_in[1];
    const float* edge_attr  = (const float*)d_in[2];
    const int*   edge_src   = (const int*)d_in[3];
    const int*   edge_dst   = (const int*)d_in[4];
    const float* user_W = (const float*)d_in[5];
    const float* user_b = (const float*)d_in[6];
    const float* item_W = (const float*)d_in[7];
    const float* item_b = (const float*)d_in[8];
    const float* c1_Wl  = (const float*)d_in[9];
    const float* c1_bl  = (const float*)d_in[10];
    const float* c1_Wr  = (const float*)d_in[11];
    const float* c1_br  = (const float*)d_in[12];
    const float* c1_We  = (const float*)d_in[13];
    const float* c1_att = (const float*)d_in[14];
    const float* c1_bias= (const float*)d_in[15];
    const float* c2_Wl  = (const float*)d_in[16];
    const float* c2_bl  = (const float*)d_in[17];
    const float* c2_Wr  = (const float*)d_in[18];
    const float* c2_br  = (const float*)d_in[19];
    const float* c2_att = (const float*)d_in[20];
    const float* c2_bias= (const float*)d_in[21];
    const float* cls_W1 = (const float*)d_in[22];
    const float* cls_b1 = (const float*)d_in[23];
    const float* cls_W2 = (const float*)d_in[24];
    const float* cls_b2 = (const float*)d_in[25];
    float* out = (float*)d_out;

    float* ws = (float*)d_ws;
    size_t off = 0;
    unsigned short* B1 = (unsigned short*)(ws + off); off += (size_t)NU * 64; // xl1 bf16
    unsigned short* B2 = (unsigned short*)(ws + off); off += (size_t)NU * 64; // xr2 bf16
    float* F = ws + off; off += (size_t)NI * HC;                              // item_h fp32
    unsigned short* G = (unsigned short*)(ws + off); off += (size_t)NI * 64;  // xl2 bf16
    int* cnt1  = (int*)(ws + off); off += NI;
    int* off1  = (int*)(ws + off); off += NI;
    int* cnt2  = (int*)(ws + off); off += NU;
    int* off2  = (int*)(ws + off); off += NU;
    int* bs    = (int*)(ws + off); off += 1024;
    int* bss   = (int*)(ws + off); off += 1024;
    uint4* sE1 = (uint4*)(ws + off); off += (size_t)NE * 4;
    int* sFund = (int*)(ws + off); off += NE;
    int* rankU = (int*)(ws + off); off += NE;
    int* rankI = (int*)(ws + off); off += NE;
    unsigned short* Bp = (unsigned short*)(ws + off); off += 12288 + 256;     // 96KB frags
    unsigned short* Bp1 = (unsigned short*)(ws + off); off += 4096 + 256;     // 16KB W1 frags
    float* wvbb = ws + off; off += 256;

    hipMemsetAsync(cnt1, 0, NI * sizeof(int), stream);
    hipMemsetAsync(cnt2, 0, NU * sizeof(int), stream);

    // weight prep first (Bp needed by both hybrid kernels)
    wprep<<<192, 256, 0, stream>>>(user_W, user_b, c1_Wl, c1_bl,
                                   c2_Wr, c2_br, c2_Wl, Bp);
    w1prep<<<32, 256, 0, stream>>>(cls_W1, Bp1);
    wvbb_prep<<<1, 128, 0, stream>>>(item_W, item_b, c1_Wr, c1_br, wvbb);

    // PHASE 1: histogram+rank (blocks 0..1024) || MFMA rows [0, 249984)
    const int nubA = 3906;                 // rows 0 .. 249984
    hist_mfma<<<1024 + nubA, 256, 0, stream>>>(
        edge_src, edge_dst, cnt2, cnt1, rankU, rankI, NE, 1024,
        customer_x, Bp, B1, B2, nubA * 64);

    // scans
    const int nb1 = (NI + 1023) / 1024;
    const int nb2 = (NU + 1023) / 1024;
    scan_blocks<<<nb1, 256, 0, stream>>>(cnt1, off1, bs, NI);
    scan_blocks<<<1,   256, 0, stream>>>(bs, bss, nullptr, nb1);
    scan_add<<<nb1, 256, 0, stream>>>(off1, bss, NI);
    scan_blocks<<<nb2, 256, 0, stream>>>(cnt2, off2, bs, NU);
    scan_blocks<<<1,   256, 0, stream>>>(bs, bss, nullptr, nb2);
    scan_add<<<nb2, 256, 0, stream>>>(off2, bss, NU);

    // PHASE 2: scatter (blocks 0..2048) || MFMA rows [249984, 500000)
    const int rowoff = nubA * 64;          // 249984
    const int nubB = (NU - rowoff + 63) / 64;   // 3907
    scat_mfma<<<2048 + nubB, 256, 0, stream>>>(
        edge_src, edge_dst, edge_attr, off2, off1, rankU, rankI,
        sFund, sE1, NE, 2048,
        customer_x, Bp, B1, B2, NU, rowoff);

    // conv1: customer -> fund (+bias+relu), xr1 on-the-fly, fp32 out F
    conv1_fused<<<NI / 4, 256, 0, stream>>>((const unsigned int*)B1, fund_x, wvbb,
                                            off1, cnt1, sE1,
                                            c1_We, c1_att, c1_bias, F, NI);

    // xl2 = item_h @ c2_Wl + c2_bl (bf16)
    mfma_xl2<<<(NI / 16 + 3) / 4, 256, 0, stream>>>(F, Bp, c2_bl, G, NI);

    // conv2 + classifier fused: one wave per 16 users
    const int waves2 = (NU + 15) / 16;             // 31250
    conv2_cls<<<(waves2 + 3) / 4, 256, 0, stream>>>(
        (const unsigned int*)G, (const unsigned int*)B2, off2, cnt2, sFund,
        c2_att, c2_bias, Bp1, cls_b1, cls_W2, cls_b2, out, NU);
}